// Round 6
// baseline (508.639 us; speedup 1.0000x reference)
//
#include <hip/hip_runtime.h>
#include <hip/hip_bf16.h>

#define HIDDEN 64
#define EPS 1e-5f
#define NPB 64            // nodes per block in GEMM/layer kernels
#define WST 72            // bf16 LDS row stride (shorts): 16B-aligned, breaks 128B aliasing
#define HF 68             // f32 LDS row stride (floats)

typedef __attribute__((ext_vector_type(8))) short bf16x8;   // MFMA A/B frag (4 VGPRs)
typedef __attribute__((ext_vector_type(4))) float f32x4;    // MFMA C/D frag

__device__ __forceinline__ unsigned short f2b(float x) {
    __hip_bfloat16 b = __float2bfloat16(x);
    return *(unsigned short*)&b;
}

// ---------------- CSR build ----------------
// hist_rank: count rows AND record each edge's arrival rank (coalesced write)
// so fill needs no atomics. fill stays XCD-partitioned (class = blockIdx&7 owns
// a row range) so each ecol line is dirtied by one XCD's L2 only.

__global__ __launch_bounds__(256) void hist_rank_kernel(const int* __restrict__ row,
                                                        int* __restrict__ cnt,
                                                        int* __restrict__ erank, int e) {
    int stride = gridDim.x * blockDim.x;
    for (int i = blockIdx.x * blockDim.x + threadIdx.x; i < e; i += stride) {
        int r = row[i];
        erank[i] = atomicAdd(&cnt[r], 1);
    }
}

__global__ __launch_bounds__(256) void block_sum_kernel(const int* __restrict__ cnt,
                                                        int* __restrict__ bsum, int n) {
    __shared__ int wsum[4];
    int tid = threadIdx.x;
    int i = blockIdx.x * 256 + tid;
    int v = (i < n) ? cnt[i] : 0;
#pragma unroll
    for (int off = 32; off > 0; off >>= 1) v += __shfl_xor(v, off, 64);
    if ((tid & 63) == 0) wsum[tid >> 6] = v;
    __syncthreads();
    if (tid == 0) bsum[blockIdx.x] = wsum[0] + wsum[1] + wsum[2] + wsum[3];
}

__global__ __launch_bounds__(1024) void scan_bsum_kernel(int* __restrict__ bsum, int nb,
                                                         int* __restrict__ total_out) {
    __shared__ int wsum[16];
    __shared__ int wexcl[16];
    int tid = threadIdx.x;
    int lane = tid & 63;
    int w = tid >> 6;
    int v = (tid < nb) ? bsum[tid] : 0;
    int sc = v;
#pragma unroll
    for (int off = 1; off < 64; off <<= 1) {
        int t = __shfl_up(sc, off, 64);
        if (lane >= off) sc += t;
    }
    if (lane == 63) wsum[w] = sc;
    __syncthreads();
    if (tid == 0) {
        int a = 0;
#pragma unroll
        for (int j = 0; j < 16; j++) { wexcl[j] = a; a += wsum[j]; }
        *total_out = a;
    }
    __syncthreads();
    if (tid < nb) bsum[tid] = wexcl[w] + (sc - v);
}

__global__ __launch_bounds__(256) void scan_final_kernel(const int* __restrict__ cnt,
                                                         const int* __restrict__ bexcl,
                                                         int* __restrict__ row_ptr, int n) {
    __shared__ int wsum[4];
    __shared__ int wexcl[4];
    int tid = threadIdx.x;
    int lane = tid & 63;
    int w = tid >> 6;
    int i = blockIdx.x * 256 + tid;
    int v = (i < n) ? cnt[i] : 0;
    int sc = v;
#pragma unroll
    for (int off = 1; off < 64; off <<= 1) {
        int t = __shfl_up(sc, off, 64);
        if (lane >= off) sc += t;
    }
    if (lane == 63) wsum[w] = sc;
    __syncthreads();
    if (tid == 0) {
        int a = 0;
#pragma unroll
        for (int j = 0; j < 4; j++) { wexcl[j] = a; a += wsum[j]; }
    }
    __syncthreads();
    if (i < n) row_ptr[i] = bexcl[blockIdx.x] + wexcl[w] + (sc - v);
}

// atomic-free fill: pos = row_ptr[r] + erank[i]
__global__ __launch_bounds__(256) void fill_kernel(const int* __restrict__ row,
                                                   const int* __restrict__ col,
                                                   const int* __restrict__ row_ptr,
                                                   const int* __restrict__ erank,
                                                   int* __restrict__ ecol, int e, int n) {
    int cls = blockIdx.x & 7;
    int sub = blockIdx.x >> 3;
    int nsub = gridDim.x >> 3;
    int lo = (int)(((long long)n * cls) >> 3);
    int hi = (int)(((long long)n * (cls + 1)) >> 3);
    for (int i = sub * 256 + threadIdx.x; i < e; i += nsub * 256) {
        int r = row[i];
        if (r >= lo && r < hi) {
            int pos = row_ptr[r] + erank[i];
            ecol[pos] = col[i];
        }
    }
}

// ---------------- MFMA helpers ----------------
// A tile: s_a[node][k] bf16 stride WST; wave computes nodes wbase..wbase+15.
// B tile: s_b[o][k] bf16 stride WST (weights are [o][k] row-major = B layout).
// D layout: col=l16 (output), row=quad*4+reg (node).  [verified m89/m91]

__device__ __forceinline__ void mfma_tile(const unsigned short* s_a,
                                          const unsigned short* s_b,
                                          int l16, int quad, int wbase, f32x4 acc[4]) {
    const unsigned short* ap = &s_a[(size_t)(wbase + l16) * WST + quad * 8];
    const unsigned short* bp = &s_b[(size_t)l16 * WST + quad * 8];
#pragma unroll
    for (int kt = 0; kt < 2; kt++) {
        bf16x8 a = *(const bf16x8*)(ap + kt * 32);
#pragma unroll
        for (int nt = 0; nt < 4; nt++) {
            bf16x8 b = *(const bf16x8*)(bp + (size_t)nt * 16 * WST + kt * 32);
            acc[nt] = __builtin_amdgcn_mfma_f32_16x16x32_bf16(a, b, acc[nt], 0, 0, 0);
        }
    }
}

// stage one 64x64 f32 weight matrix -> bf16 LDS tile [o][k], stride WST
__device__ __forceinline__ void stage_w(const float* __restrict__ w,
                                        unsigned short* s_wb, int tid) {
    for (int i = tid; i < 512; i += 256) {
        int r = i >> 3, seg = i & 7;
        const float4* wp = (const float4*)(w + r * 64 + seg * 8);
        float4 wa = wp[0], wb = wp[1];
        uint4 p;
        p.x = (unsigned int)f2b(wa.x) | ((unsigned int)f2b(wa.y) << 16);
        p.y = (unsigned int)f2b(wa.z) | ((unsigned int)f2b(wa.w) << 16);
        p.z = (unsigned int)f2b(wb.x) | ((unsigned int)f2b(wb.y) << 16);
        p.w = (unsigned int)f2b(wb.z) | ((unsigned int)f2b(wb.w) << 16);
        *(uint4*)(&s_wb[r * WST + seg * 8]) = p;
    }
}

// ---------------- initial conv matmul: m = bf16(relu(x @ cw0^T)) ----------------

__global__ __launch_bounds__(256) void mm_relu_kernel(const float* __restrict__ h,
                                                      const float* __restrict__ w,
                                                      __hip_bfloat16* __restrict__ m, int n) {
    __shared__ unsigned short s_hb[NPB * WST];
    __shared__ unsigned short s_wb[64 * WST];
    int tid = threadIdx.x;
    int base = blockIdx.x * NPB;
    stage_w(w, s_wb, tid);
    for (int i = tid; i < 512; i += 256) {
        int r = i >> 3, seg = i & 7;
        uint4 p = make_uint4(0u, 0u, 0u, 0u);
        if (base + r < n) {
            const float4* hp = (const float4*)(h + (size_t)(base + r) * HIDDEN + seg * 8);
            float4 ha = hp[0], hb = hp[1];
            p.x = (unsigned int)f2b(ha.x) | ((unsigned int)f2b(ha.y) << 16);
            p.y = (unsigned int)f2b(ha.z) | ((unsigned int)f2b(ha.w) << 16);
            p.z = (unsigned int)f2b(hb.x) | ((unsigned int)f2b(hb.y) << 16);
            p.w = (unsigned int)f2b(hb.z) | ((unsigned int)f2b(hb.w) << 16);
        }
        *(uint4*)(&s_hb[r * WST + seg * 8]) = p;
    }
    __syncthreads();
    int lane = tid & 63, wave = tid >> 6;
    int quad = lane >> 4, l16 = lane & 15;
    int wbase = wave * 16;
    f32x4 acc[4];
    acc[0] = (f32x4){0.f,0.f,0.f,0.f}; acc[1] = (f32x4){0.f,0.f,0.f,0.f};
    acc[2] = (f32x4){0.f,0.f,0.f,0.f}; acc[3] = (f32x4){0.f,0.f,0.f,0.f};
    mfma_tile(s_hb, s_wb, l16, quad, wbase, acc);
    unsigned short* mo = (unsigned short*)m;
#pragma unroll
    for (int r = 0; r < 4; r++) {
        int node = base + wbase + quad * 4 + r;
        if (node < n) {
#pragma unroll
            for (int nt = 0; nt < 4; nt++)
                mo[(size_t)node * HIDDEN + nt * 16 + l16] = f2b(fmaxf(acc[nt][r], 0.f));
        }
    }
}

// ---------------- fused layer kernel ----------------
// Phase A: per-wave aggregation of 16 nodes (lane=channel, 8-gather MLP),
//          conv rmsnorm -> h' into LDS (f32 residual copy + bf16 A-tile).
// Phase B: MFMA hidden GEMM + residual (LDS f32) + rmsnorm -> h_new:
//          write f32 to global h, bf16 back into s_hb (D->A via LDS).
// Phase C: MFMA with next layer's conv weights -> relu -> m_out (skipped last layer).

__global__ __launch_bounds__(256) void layer_kernel(const float* hin, float* hout,
                                                    const __hip_bfloat16* __restrict__ m_in,
                                                    __hip_bfloat16* __restrict__ m_out,
                                                    const int* __restrict__ row_ptr,
                                                    const int* __restrict__ ecol,
                                                    const float* __restrict__ cnw,
                                                    const float* __restrict__ hnw,
                                                    const float* __restrict__ hw,
                                                    const float* cw_next, int n) {
    __shared__ unsigned short s_hb[NPB * WST];   // bf16 A-tile
    __shared__ unsigned short s_wb[64 * WST];    // hidden weights
    __shared__ unsigned short s_wb2[64 * WST];   // next conv weights
    __shared__ float s_hf[NPB * HF];             // f32 h' (residual precision)

    int tid = threadIdx.x;
    int base = blockIdx.x * NPB;
    int lane = tid & 63, wave = tid >> 6;
    int wbase = wave * 16;

    stage_w(hw, s_wb, tid);
    if (cw_next) stage_w(cw_next, s_wb2, tid);

    // ---- Phase A ----
    float cs = cnw[lane];
    const unsigned short* mi = (const unsigned short*)m_in;
    for (int j = 0; j < 16; j++) {
        int node = base + wbase + j;           // wave-uniform
        float s = 0.f;
        if (node < n) {
            int beg = row_ptr[node];
            int end = row_ptr[node + 1];
            s = hin[(size_t)node * HIDDEN + lane];
            float acc[8];
#pragma unroll
            for (int q = 0; q < 8; q++) acc[q] = 0.f;
            for (int bb = beg; bb < end; bb += 8) {
                int c[8];
#pragma unroll
                for (int q = 0; q < 8; q++) {
                    int idx = bb + q;
                    c[q] = ecol[idx < end ? idx : end - 1];
                }
                float v[8];
#pragma unroll
                for (int q = 0; q < 8; q++) {
                    unsigned short u = mi[(size_t)c[q] * HIDDEN + lane];
                    unsigned int ui = (unsigned int)u << 16;
                    v[q] = *(float*)&ui;
                }
#pragma unroll
                for (int q = 0; q < 8; q++)
                    acc[q] += (bb + q < end) ? v[q] : 0.f;
            }
            s += (((acc[0] + acc[1]) + (acc[2] + acc[3])) +
                  ((acc[4] + acc[5]) + (acc[6] + acc[7])));
            float ss = s * s;
#pragma unroll
            for (int off = 32; off > 0; off >>= 1) ss += __shfl_xor(ss, off, 64);
            float inv = rsqrtf(ss * (1.0f / 64.0f) + EPS);
            s = s * inv * cs;
        }
        s_hf[(wbase + j) * HF + lane] = s;
        s_hb[(wbase + j) * WST + lane] = f2b(s);
    }
    __syncthreads();

    // ---- Phase B ----
    int quad = lane >> 4, l16 = lane & 15;
    f32x4 acc[4];
    acc[0] = (f32x4){0.f,0.f,0.f,0.f}; acc[1] = (f32x4){0.f,0.f,0.f,0.f};
    acc[2] = (f32x4){0.f,0.f,0.f,0.f}; acc[3] = (f32x4){0.f,0.f,0.f,0.f};
    mfma_tile(s_hb, s_wb, l16, quad, wbase, acc);

    float hv[4][4];
    float ssq[4] = {0.f, 0.f, 0.f, 0.f};
#pragma unroll
    for (int r = 0; r < 4; r++) {
        int nl = wbase + quad * 4 + r;
#pragma unroll
        for (int nt = 0; nt < 4; nt++) {
            float hres = s_hf[nl * HF + nt * 16 + l16];
            float v = hres + fmaxf(acc[nt][r], 0.f);
            hv[r][nt] = v;
            ssq[r] += v * v;
        }
    }
#pragma unroll
    for (int mk = 1; mk <= 8; mk <<= 1) {
#pragma unroll
        for (int r = 0; r < 4; r++) ssq[r] += __shfl_xor(ssq[r], mk, 64);
    }
    float nwv[4];
#pragma unroll
    for (int nt = 0; nt < 4; nt++) nwv[nt] = hnw[nt * 16 + l16];
#pragma unroll
    for (int r = 0; r < 4; r++) {
        float inv = rsqrtf(ssq[r] * (1.0f / 64.0f) + EPS);
#pragma unroll
        for (int nt = 0; nt < 4; nt++) hv[r][nt] *= inv * nwv[nt];
    }
#pragma unroll
    for (int r = 0; r < 4; r++) {
        int node = base + wbase + quad * 4 + r;
        if (node < n) {
#pragma unroll
            for (int nt = 0; nt < 4; nt++)
                hout[(size_t)node * HIDDEN + nt * 16 + l16] = hv[r][nt];
        }
    }
    __syncthreads();   // all waves done reading s_hb/s_hf

    if (!m_out) return;

    // ---- D -> A layout via LDS ----
#pragma unroll
    for (int r = 0; r < 4; r++) {
        int nl = wbase + quad * 4 + r;
#pragma unroll
        for (int nt = 0; nt < 4; nt++)
            s_hb[nl * WST + nt * 16 + l16] = f2b(hv[r][nt]);
    }
    __syncthreads();

    // ---- Phase C ----
    f32x4 acc2[4];
    acc2[0] = (f32x4){0.f,0.f,0.f,0.f}; acc2[1] = (f32x4){0.f,0.f,0.f,0.f};
    acc2[2] = (f32x4){0.f,0.f,0.f,0.f}; acc2[3] = (f32x4){0.f,0.f,0.f,0.f};
    mfma_tile(s_hb, s_wb2, l16, quad, wbase, acc2);
    unsigned short* mo = (unsigned short*)m_out;
#pragma unroll
    for (int r = 0; r < 4; r++) {
        int node = base + wbase + quad * 4 + r;
        if (node < n) {
#pragma unroll
            for (int nt = 0; nt < 4; nt++)
                mo[(size_t)node * HIDDEN + nt * 16 + l16] = f2b(fmaxf(acc2[nt][r], 0.f));
        }
    }
}

// ---------------- launch ----------------

static inline size_t align_up(size_t x, size_t a) { return (x + a - 1) & ~(a - 1); }

extern "C" void kernel_launch(void* const* d_in, const int* in_sizes, int n_in,
                              void* d_out, int out_size, void* d_ws, size_t ws_size,
                              hipStream_t stream) {
    const float* x       = (const float*)d_in[0];
    const float* conv_w  = (const float*)d_in[1];
    const float* conv_nw = (const float*)d_in[2];
    const float* hid_w   = (const float*)d_in[3];
    const float* hid_nw  = (const float*)d_in[4];
    const int*   row     = (const int*)d_in[5];
    const int*   col     = (const int*)d_in[6];
    float* out = (float*)d_out;

    const int n = in_sizes[0] / HIDDEN;   // 100000
    const int e = in_sizes[5];            // 800000
    const int L = in_sizes[1] / 4096;     // 4

    // workspace layout
    size_t off = 0;
    char* ws = (char*)d_ws;
    __hip_bfloat16* mA = (__hip_bfloat16*)(ws + off); off = align_up(off + (size_t)n * HIDDEN * 2, 16);
    __hip_bfloat16* mB = (__hip_bfloat16*)(ws + off); off = align_up(off + (size_t)n * HIDDEN * 2, 16);
    int* row_ptr = (int*)(ws + off);           off = align_up(off + (size_t)(n + 1) * 4, 16);
    int* cnt = (int*)(ws + off);               off = align_up(off + (size_t)n * 4, 16);
    int* bsum = (int*)(ws + off);              off = align_up(off + (size_t)1024 * 4, 16);
    int* erank = (int*)(ws + off);             off = align_up(off + (size_t)e * 4, 16);
    int* ecol = (int*)(ws + off);              off = align_up(off + (size_t)e * 4, 16);

    const int nb = (n + 255) / 256;

    // CSR build (once per launch; edges constant across layers)
    hipMemsetAsync(cnt, 0, (size_t)n * 4, stream);
    hist_rank_kernel<<<1024, 256, 0, stream>>>(row, cnt, erank, e);
    block_sum_kernel<<<nb, 256, 0, stream>>>(cnt, bsum, n);
    scan_bsum_kernel<<<1, 1024, 0, stream>>>(bsum, nb, row_ptr + n);
    scan_final_kernel<<<nb, 256, 0, stream>>>(cnt, bsum, row_ptr, n);
    fill_kernel<<<1024, 256, 0, stream>>>(row, col, row_ptr, erank, ecol, e, n);

    const int blocks = (n + NPB - 1) / NPB;

    // initial conv matmul for layer 0
    mm_relu_kernel<<<blocks, 256, 0, stream>>>(x, conv_w, mA, n);

    const __hip_bfloat16* mi = mA;
    __hip_bfloat16* mo = mB;
    const float* hcur = x;
    for (int l = 0; l < L; l++) {
        layer_kernel<<<blocks, 256, 0, stream>>>(
            hcur, out, mi, (l < L - 1) ? mo : nullptr, row_ptr, ecol,
            conv_nw + (size_t)l * HIDDEN, hid_nw + (size_t)l * HIDDEN,
            hid_w + (size_t)l * 4096,
            (l < L - 1) ? (conv_w + (size_t)(l + 1) * 4096) : nullptr, n);
        __hip_bfloat16* tmp = (__hip_bfloat16*)mi; mi = mo; mo = tmp;
        hcur = out;
    }
}

// Round 7
// 346.422 us; speedup vs baseline: 1.4683x; 1.4683x over previous
//
#include <hip/hip_runtime.h>
#include <hip/hip_bf16.h>

#define HIDDEN 64
#define EPS 1e-5f
#define NPB 64            // nodes per block in GEMM kernels
#define WST 72            // bf16 LDS row stride (shorts): 16B-aligned, breaks 128B aliasing

typedef __attribute__((ext_vector_type(8))) short bf16x8;   // MFMA A/B frag (4 VGPRs)
typedef __attribute__((ext_vector_type(4))) float f32x4;    // MFMA C/D frag

__device__ __forceinline__ unsigned short f2b(float x) {
    __hip_bfloat16 b = __float2bfloat16(x);
    return *(unsigned short*)&b;
}
__device__ __forceinline__ float b2f(unsigned short u) {
    unsigned int ui = (unsigned int)u << 16;
    return *(float*)&ui;
}

// ---------------- CSR build ----------------
// hist_rank: count rows AND record each edge's arrival rank (coalesced write)
// so fill needs no atomics. fill is XCD-partitioned (class = blockIdx&7 owns a
// row range) so each ecol line is dirtied by one XCD's L2 only.

__global__ __launch_bounds__(256) void hist_rank_kernel(const int* __restrict__ row,
                                                        int* __restrict__ cnt,
                                                        int* __restrict__ erank, int e) {
    int stride = gridDim.x * blockDim.x;
    for (int i = blockIdx.x * blockDim.x + threadIdx.x; i < e; i += stride) {
        int r = row[i];
        erank[i] = atomicAdd(&cnt[r], 1);
    }
}

__global__ __launch_bounds__(256) void block_sum_kernel(const int* __restrict__ cnt,
                                                        int* __restrict__ bsum, int n) {
    __shared__ int wsum[4];
    int tid = threadIdx.x;
    int i = blockIdx.x * 256 + tid;
    int v = (i < n) ? cnt[i] : 0;
#pragma unroll
    for (int off = 32; off > 0; off >>= 1) v += __shfl_xor(v, off, 64);
    if ((tid & 63) == 0) wsum[tid >> 6] = v;
    __syncthreads();
    if (tid == 0) bsum[blockIdx.x] = wsum[0] + wsum[1] + wsum[2] + wsum[3];
}

__global__ __launch_bounds__(1024) void scan_bsum_kernel(int* __restrict__ bsum, int nb,
                                                         int* __restrict__ total_out) {
    __shared__ int wsum[16];
    __shared__ int wexcl[16];
    int tid = threadIdx.x;
    int lane = tid & 63;
    int w = tid >> 6;
    int v = (tid < nb) ? bsum[tid] : 0;
    int sc = v;
#pragma unroll
    for (int off = 1; off < 64; off <<= 1) {
        int t = __shfl_up(sc, off, 64);
        if (lane >= off) sc += t;
    }
    if (lane == 63) wsum[w] = sc;
    __syncthreads();
    if (tid == 0) {
        int a = 0;
#pragma unroll
        for (int j = 0; j < 16; j++) { wexcl[j] = a; a += wsum[j]; }
        *total_out = a;
    }
    __syncthreads();
    if (tid < nb) bsum[tid] = wexcl[w] + (sc - v);
}

__global__ __launch_bounds__(256) void scan_final_kernel(const int* __restrict__ cnt,
                                                         const int* __restrict__ bexcl,
                                                         int* __restrict__ row_ptr, int n) {
    __shared__ int wsum[4];
    __shared__ int wexcl[4];
    int tid = threadIdx.x;
    int lane = tid & 63;
    int w = tid >> 6;
    int i = blockIdx.x * 256 + tid;
    int v = (i < n) ? cnt[i] : 0;
    int sc = v;
#pragma unroll
    for (int off = 1; off < 64; off <<= 1) {
        int t = __shfl_up(sc, off, 64);
        if (lane >= off) sc += t;
    }
    if (lane == 63) wsum[w] = sc;
    __syncthreads();
    if (tid == 0) {
        int a = 0;
#pragma unroll
        for (int j = 0; j < 4; j++) { wexcl[j] = a; a += wsum[j]; }
    }
    __syncthreads();
    if (i < n) row_ptr[i] = bexcl[blockIdx.x] + wexcl[w] + (sc - v);
}

__global__ __launch_bounds__(256) void fill_kernel(const int* __restrict__ row,
                                                   const int* __restrict__ col,
                                                   const int* __restrict__ row_ptr,
                                                   const int* __restrict__ erank,
                                                   int* __restrict__ ecol, int e, int n) {
    int cls = blockIdx.x & 7;
    int sub = blockIdx.x >> 3;
    int nsub = gridDim.x >> 3;
    int lo = (int)(((long long)n * cls) >> 3);
    int hi = (int)(((long long)n * (cls + 1)) >> 3);
    for (int i = sub * 256 + threadIdx.x; i < e; i += nsub * 256) {
        int r = row[i];
        if (r >= lo && r < hi) {
            int pos = row_ptr[r] + erank[i];
            ecol[pos] = col[i];
        }
    }
}

// ---------------- MFMA helpers ----------------
// A tile: s_a[node][k] bf16 stride WST; wave computes nodes wbase..wbase+15.
// B tile: s_b[o][k] bf16 stride WST (weights [o][k] row-major = B layout).
// D layout: col=l16 (output), row=quad*4+reg (node).  [verified m89/m91]

__device__ __forceinline__ void mfma_tile(const unsigned short* s_a,
                                          const unsigned short* s_b,
                                          int l16, int quad, int wbase, f32x4 acc[4]) {
    const unsigned short* ap = &s_a[(size_t)(wbase + l16) * WST + quad * 8];
    const unsigned short* bp = &s_b[(size_t)l16 * WST + quad * 8];
#pragma unroll
    for (int kt = 0; kt < 2; kt++) {
        bf16x8 a = *(const bf16x8*)(ap + kt * 32);
#pragma unroll
        for (int nt = 0; nt < 4; nt++) {
            bf16x8 b = *(const bf16x8*)(bp + (size_t)nt * 16 * WST + kt * 32);
            acc[nt] = __builtin_amdgcn_mfma_f32_16x16x32_bf16(a, b, acc[nt], 0, 0, 0);
        }
    }
}

// stage one 64x64 f32 weight matrix -> bf16 LDS tile [o][k], stride WST
__device__ __forceinline__ void stage_w(const float* __restrict__ w,
                                        unsigned short* s_wb, int tid) {
    for (int i = tid; i < 512; i += 256) {
        int r = i >> 3, seg = i & 7;
        const float4* wp = (const float4*)(w + r * 64 + seg * 8);
        float4 wa = wp[0], wb = wp[1];
        uint4 p;
        p.x = (unsigned int)f2b(wa.x) | ((unsigned int)f2b(wa.y) << 16);
        p.y = (unsigned int)f2b(wa.z) | ((unsigned int)f2b(wa.w) << 16);
        p.z = (unsigned int)f2b(wb.x) | ((unsigned int)f2b(wb.y) << 16);
        p.w = (unsigned int)f2b(wb.z) | ((unsigned int)f2b(wb.w) << 16);
        *(uint4*)(&s_wb[r * WST + seg * 8]) = p;
    }
}

// ---------------- initial conv matmul: m = bf16(relu(x @ cw0^T)) ----------------

__global__ __launch_bounds__(256) void mm_relu_kernel(const float* __restrict__ h,
                                                      const float* __restrict__ w,
                                                      __hip_bfloat16* __restrict__ m, int n) {
    __shared__ unsigned short s_hb[NPB * WST];
    __shared__ unsigned short s_wb[64 * WST];
    int tid = threadIdx.x;
    int base = blockIdx.x * NPB;
    stage_w(w, s_wb, tid);
    for (int i = tid; i < 512; i += 256) {
        int r = i >> 3, seg = i & 7;
        uint4 p = make_uint4(0u, 0u, 0u, 0u);
        if (base + r < n) {
            const float4* hp = (const float4*)(h + (size_t)(base + r) * HIDDEN + seg * 8);
            float4 ha = hp[0], hb = hp[1];
            p.x = (unsigned int)f2b(ha.x) | ((unsigned int)f2b(ha.y) << 16);
            p.y = (unsigned int)f2b(ha.z) | ((unsigned int)f2b(ha.w) << 16);
            p.z = (unsigned int)f2b(hb.x) | ((unsigned int)f2b(hb.y) << 16);
            p.w = (unsigned int)f2b(hb.z) | ((unsigned int)f2b(hb.w) << 16);
        }
        *(uint4*)(&s_hb[r * WST + seg * 8]) = p;
    }
    __syncthreads();
    int lane = tid & 63, wave = tid >> 6;
    int quad = lane >> 4, l16 = lane & 15;
    int wbase = wave * 16;
    f32x4 acc[4];
    acc[0] = (f32x4){0.f,0.f,0.f,0.f}; acc[1] = (f32x4){0.f,0.f,0.f,0.f};
    acc[2] = (f32x4){0.f,0.f,0.f,0.f}; acc[3] = (f32x4){0.f,0.f,0.f,0.f};
    mfma_tile(s_hb, s_wb, l16, quad, wbase, acc);
    unsigned short* mo = (unsigned short*)m;
#pragma unroll
    for (int r = 0; r < 4; r++) {
        int node = base + wbase + quad * 4 + r;
        if (node < n) {
#pragma unroll
            for (int nt = 0; nt < 4; nt++)
                mo[(size_t)node * HIDDEN + nt * 16 + l16] = f2b(fmaxf(acc[nt][r], 0.f));
        }
    }
}

// ---------------- aggregation ----------------
// out[node] = rmsnorm(h[node] + sum_e m[ecol[e]], nw). One wave per node,
// lane = channel. Lane l bulk-loads ecol[beg+l] (one coalesced transaction =
// up to 64 edges), indices broadcast via __shfl -> gathers issue back-to-back
// with no per-batch global index dependency.
__global__ __launch_bounds__(256) void aggregate_kernel(const float* __restrict__ h,
                                                        const __hip_bfloat16* __restrict__ m,
                                                        const int* __restrict__ row_ptr,
                                                        const int* __restrict__ ecol,
                                                        const float* __restrict__ nw,
                                                        float* __restrict__ out, int n) {
    int lane = threadIdx.x & 63;
    int node = (blockIdx.x * blockDim.x + threadIdx.x) >> 6;
    if (node >= n) return;
    int beg = row_ptr[node];
    int end = row_ptr[node + 1];
    float s = h[(size_t)node * HIDDEN + lane];
    const unsigned short* mi = (const unsigned short*)m;
    float acc[8];
#pragma unroll
    for (int q = 0; q < 8; q++) acc[q] = 0.f;
    for (int b0 = beg; b0 < end; b0 += 64) {
        int idx = b0 + lane;
        int myc = ecol[idx < end ? idx : end - 1];
        int cnt = end - b0;
        if (cnt > 64) cnt = 64;
        for (int q0 = 0; q0 < cnt; q0 += 8) {
            int c[8];
#pragma unroll
            for (int j = 0; j < 8; j++) c[j] = __shfl(myc, q0 + j, 64);
            float v[8];
#pragma unroll
            for (int j = 0; j < 8; j++) v[j] = b2f(mi[(size_t)c[j] * HIDDEN + lane]);
#pragma unroll
            for (int j = 0; j < 8; j++) acc[j] += (q0 + j < cnt) ? v[j] : 0.f;
        }
    }
    s += (((acc[0] + acc[1]) + (acc[2] + acc[3])) +
          ((acc[4] + acc[5]) + (acc[6] + acc[7])));
    float ss = s * s;
#pragma unroll
    for (int off = 32; off > 0; off >>= 1) ss += __shfl_xor(ss, off, 64);
    float inv = rsqrtf(ss * (1.0f / 64.0f) + EPS);
    out[(size_t)node * HIDDEN + lane] = s * inv * nw[lane];
}

// ---------------- fused hidden + next-conv kernel ----------------
// Phase B: h_new = rmsnorm(h' + relu(h' @ hw^T), hnw)  (in place on h)
// Phase C: m_out = bf16(relu(h_new @ cw_next^T))       (skipped last layer)
// Each wave reads/writes only its own 16 LDS A-tile rows, so no barrier is
// needed between B's A-frag reads and the D->A LDS writeback. Residual h'
// read from global (L2/L3-hot, just written by aggregate).

__global__ __launch_bounds__(256) void hidden_next_kernel(float* __restrict__ h,
                                                          const float* __restrict__ hw,
                                                          const float* cw_next,
                                                          const float* __restrict__ hnw,
                                                          __hip_bfloat16* m_out, int n) {
    __shared__ unsigned short s_hb[NPB * WST];
    __shared__ unsigned short s_wb[64 * WST];
    __shared__ unsigned short s_wb2[64 * WST];
    int tid = threadIdx.x;
    int base = blockIdx.x * NPB;
    stage_w(hw, s_wb, tid);
    if (cw_next) stage_w(cw_next, s_wb2, tid);
    for (int i = tid; i < 512; i += 256) {
        int r = i >> 3, seg = i & 7;
        uint4 p = make_uint4(0u, 0u, 0u, 0u);
        if (base + r < n) {
            const float4* hp = (const float4*)(h + (size_t)(base + r) * HIDDEN + seg * 8);
            float4 ha = hp[0], hb = hp[1];
            p.x = (unsigned int)f2b(ha.x) | ((unsigned int)f2b(ha.y) << 16);
            p.y = (unsigned int)f2b(ha.z) | ((unsigned int)f2b(ha.w) << 16);
            p.z = (unsigned int)f2b(hb.x) | ((unsigned int)f2b(hb.y) << 16);
            p.w = (unsigned int)f2b(hb.z) | ((unsigned int)f2b(hb.w) << 16);
        }
        *(uint4*)(&s_hb[r * WST + seg * 8]) = p;
    }
    __syncthreads();

    int lane = tid & 63, wave = tid >> 6;
    int quad = lane >> 4, l16 = lane & 15;
    int wbase = wave * 16;

    // ---- Phase B ----
    f32x4 acc[4];
    acc[0] = (f32x4){0.f,0.f,0.f,0.f}; acc[1] = (f32x4){0.f,0.f,0.f,0.f};
    acc[2] = (f32x4){0.f,0.f,0.f,0.f}; acc[3] = (f32x4){0.f,0.f,0.f,0.f};
    mfma_tile(s_hb, s_wb, l16, quad, wbase, acc);

    float hv[4][4];
    float ssq[4] = {0.f, 0.f, 0.f, 0.f};
#pragma unroll
    for (int r = 0; r < 4; r++) {
        int node = base + wbase + quad * 4 + r;
        bool ok = node < n;
#pragma unroll
        for (int nt = 0; nt < 4; nt++) {
            float hres = ok ? h[(size_t)node * HIDDEN + nt * 16 + l16] : 0.f;
            float v = hres + fmaxf(acc[nt][r], 0.f);
            hv[r][nt] = v;
            ssq[r] += v * v;
        }
    }
#pragma unroll
    for (int mk = 1; mk <= 8; mk <<= 1) {
#pragma unroll
        for (int r = 0; r < 4; r++) ssq[r] += __shfl_xor(ssq[r], mk, 64);
    }
    float nwv[4];
#pragma unroll
    for (int nt = 0; nt < 4; nt++) nwv[nt] = hnw[nt * 16 + l16];
#pragma unroll
    for (int r = 0; r < 4; r++) {
        float inv = rsqrtf(ssq[r] * (1.0f / 64.0f) + EPS);
#pragma unroll
        for (int nt = 0; nt < 4; nt++) hv[r][nt] *= inv * nwv[nt];
    }
#pragma unroll
    for (int r = 0; r < 4; r++) {
        int node = base + wbase + quad * 4 + r;
        if (node < n) {
#pragma unroll
            for (int nt = 0; nt < 4; nt++)
                h[(size_t)node * HIDDEN + nt * 16 + l16] = hv[r][nt];
        }
    }

    if (!m_out) return;

    // ---- D -> A layout (own rows only, no barrier needed) ----
#pragma unroll
    for (int r = 0; r < 4; r++) {
        int nl = wbase + quad * 4 + r;
#pragma unroll
        for (int nt = 0; nt < 4; nt++)
            s_hb[nl * WST + nt * 16 + l16] = f2b(hv[r][nt]);
    }

    // ---- Phase C ----
    f32x4 acc2[4];
    acc2[0] = (f32x4){0.f,0.f,0.f,0.f}; acc2[1] = (f32x4){0.f,0.f,0.f,0.f};
    acc2[2] = (f32x4){0.f,0.f,0.f,0.f}; acc2[3] = (f32x4){0.f,0.f,0.f,0.f};
    mfma_tile(s_hb, s_wb2, l16, quad, wbase, acc2);
    unsigned short* mo = (unsigned short*)m_out;
#pragma unroll
    for (int r = 0; r < 4; r++) {
        int node = base + wbase + quad * 4 + r;
        if (node < n) {
#pragma unroll
            for (int nt = 0; nt < 4; nt++)
                mo[(size_t)node * HIDDEN + nt * 16 + l16] = f2b(fmaxf(acc2[nt][r], 0.f));
        }
    }
}

// ---------------- launch ----------------

static inline size_t align_up(size_t x, size_t a) { return (x + a - 1) & ~(a - 1); }

extern "C" void kernel_launch(void* const* d_in, const int* in_sizes, int n_in,
                              void* d_out, int out_size, void* d_ws, size_t ws_size,
                              hipStream_t stream) {
    const float* x       = (const float*)d_in[0];
    const float* conv_w  = (const float*)d_in[1];
    const float* conv_nw = (const float*)d_in[2];
    const float* hid_w   = (const float*)d_in[3];
    const float* hid_nw  = (const float*)d_in[4];
    const int*   row     = (const int*)d_in[5];
    const int*   col     = (const int*)d_in[6];
    float* out = (float*)d_out;

    const int n = in_sizes[0] / HIDDEN;   // 100000
    const int e = in_sizes[5];            // 800000
    const int L = in_sizes[1] / 4096;     // 4

    // workspace layout
    size_t off = 0;
    char* ws = (char*)d_ws;
    __hip_bfloat16* mA = (__hip_bfloat16*)(ws + off); off = align_up(off + (size_t)n * HIDDEN * 2, 16);
    __hip_bfloat16* mB = (__hip_bfloat16*)(ws + off); off = align_up(off + (size_t)n * HIDDEN * 2, 16);
    int* row_ptr = (int*)(ws + off);           off = align_up(off + (size_t)(n + 1) * 4, 16);
    int* cnt = (int*)(ws + off);               off = align_up(off + (size_t)n * 4, 16);
    int* bsum = (int*)(ws + off);              off = align_up(off + (size_t)1024 * 4, 16);
    int* erank = (int*)(ws + off);             off = align_up(off + (size_t)e * 4, 16);
    int* ecol = (int*)(ws + off);              off = align_up(off + (size_t)e * 4, 16);

    const int nb = (n + 255) / 256;

    // CSR build (once per launch; edges constant across layers)
    hipMemsetAsync(cnt, 0, (size_t)n * 4, stream);
    hist_rank_kernel<<<1024, 256, 0, stream>>>(row, cnt, erank, e);
    block_sum_kernel<<<nb, 256, 0, stream>>>(cnt, bsum, n);
    scan_bsum_kernel<<<1, 1024, 0, stream>>>(bsum, nb, row_ptr + n);
    scan_final_kernel<<<nb, 256, 0, stream>>>(cnt, bsum, row_ptr, n);
    fill_kernel<<<1024, 256, 0, stream>>>(row, col, row_ptr, erank, ecol, e, n);

    const int blocks = (n + NPB - 1) / NPB;
    const int agg_blocks = (n * 64 + 255) / 256;   // one wave per node

    // initial conv matmul for layer 0
    mm_relu_kernel<<<blocks, 256, 0, stream>>>(x, conv_w, mA, n);

    const __hip_bfloat16* mi = mA;
    __hip_bfloat16* mo = mB;
    const float* hcur = x;
    for (int l = 0; l < L; l++) {
        aggregate_kernel<<<agg_blocks, 256, 0, stream>>>(hcur, mi, row_ptr, ecol,
                                                         conv_nw + (size_t)l * HIDDEN, out, n);
        hidden_next_kernel<<<blocks, 256, 0, stream>>>(
            out, hid_w + (size_t)l * 4096,
            (l < L - 1) ? (conv_w + (size_t)(l + 1) * 4096) : nullptr,
            hid_nw + (size_t)l * HIDDEN,
            (l < L - 1) ? mo : nullptr, n);
        __hip_bfloat16* tmp = (__hip_bfloat16*)mi; mi = mo; mo = tmp;
        hcur = out;
    }
}

// Round 8
// 316.180 us; speedup vs baseline: 1.6087x; 1.0957x over previous
//
#include <hip/hip_runtime.h>
#include <hip/hip_bf16.h>

#define HIDDEN 64
#define EPS 1e-5f
#define NPB 64            // nodes per block in GEMM kernels
#define WST 72            // bf16 LDS row stride (shorts): 16B-aligned, breaks 128B aliasing

typedef __attribute__((ext_vector_type(8))) short bf16x8;   // MFMA A/B frag (4 VGPRs)
typedef __attribute__((ext_vector_type(4))) float f32x4;    // MFMA C/D frag

__device__ __forceinline__ unsigned short f2b(float x) {
    __hip_bfloat16 b = __float2bfloat16(x);
    return *(unsigned short*)&b;
}
__device__ __forceinline__ float b2f(unsigned short u) {
    unsigned int ui = (unsigned int)u << 16;
    return *(float*)&ui;
}

// ---------------- CSR build ----------------

__global__ __launch_bounds__(256) void hist_rank_kernel(const int* __restrict__ row,
                                                        int* __restrict__ cnt,
                                                        int* __restrict__ erank, int e) {
    int stride = gridDim.x * blockDim.x;
    for (int i = blockIdx.x * blockDim.x + threadIdx.x; i < e; i += stride) {
        int r = row[i];
        erank[i] = atomicAdd(&cnt[r], 1);
    }
}

__global__ __launch_bounds__(256) void block_sum_kernel(const int* __restrict__ cnt,
                                                        int* __restrict__ bsum, int n) {
    __shared__ int wsum[4];
    int tid = threadIdx.x;
    int i = blockIdx.x * 256 + tid;
    int v = (i < n) ? cnt[i] : 0;
#pragma unroll
    for (int off = 32; off > 0; off >>= 1) v += __shfl_xor(v, off, 64);
    if ((tid & 63) == 0) wsum[tid >> 6] = v;
    __syncthreads();
    if (tid == 0) bsum[blockIdx.x] = wsum[0] + wsum[1] + wsum[2] + wsum[3];
}

__global__ __launch_bounds__(1024) void scan_bsum_kernel(int* __restrict__ bsum, int nb,
                                                         int* __restrict__ total_out) {
    __shared__ int wsum[16];
    __shared__ int wexcl[16];
    int tid = threadIdx.x;
    int lane = tid & 63;
    int w = tid >> 6;
    int v = (tid < nb) ? bsum[tid] : 0;
    int sc = v;
#pragma unroll
    for (int off = 1; off < 64; off <<= 1) {
        int t = __shfl_up(sc, off, 64);
        if (lane >= off) sc += t;
    }
    if (lane == 63) wsum[w] = sc;
    __syncthreads();
    if (tid == 0) {
        int a = 0;
#pragma unroll
        for (int j = 0; j < 16; j++) { wexcl[j] = a; a += wsum[j]; }
        *total_out = a;
    }
    __syncthreads();
    if (tid < nb) bsum[tid] = wexcl[w] + (sc - v);
}

__global__ __launch_bounds__(256) void scan_final_kernel(const int* __restrict__ cnt,
                                                         const int* __restrict__ bexcl,
                                                         int* __restrict__ row_ptr, int n) {
    __shared__ int wsum[4];
    __shared__ int wexcl[4];
    int tid = threadIdx.x;
    int lane = tid & 63;
    int w = tid >> 6;
    int i = blockIdx.x * 256 + tid;
    int v = (i < n) ? cnt[i] : 0;
    int sc = v;
#pragma unroll
    for (int off = 1; off < 64; off <<= 1) {
        int t = __shfl_up(sc, off, 64);
        if (lane >= off) sc += t;
    }
    if (lane == 63) wsum[w] = sc;
    __syncthreads();
    if (tid == 0) {
        int a = 0;
#pragma unroll
        for (int j = 0; j < 4; j++) { wexcl[j] = a; a += wsum[j]; }
    }
    __syncthreads();
    if (i < n) row_ptr[i] = bexcl[blockIdx.x] + wexcl[w] + (sc - v);
}

__global__ __launch_bounds__(256) void fill_kernel(const int* __restrict__ row,
                                                   const int* __restrict__ col,
                                                   const int* __restrict__ row_ptr,
                                                   const int* __restrict__ erank,
                                                   int* __restrict__ ecol, int e, int n) {
    int cls = blockIdx.x & 7;
    int sub = blockIdx.x >> 3;
    int nsub = gridDim.x >> 3;
    int lo = (int)(((long long)n * cls) >> 3);
    int hi = (int)(((long long)n * (cls + 1)) >> 3);
    for (int i = sub * 256 + threadIdx.x; i < e; i += nsub * 256) {
        int r = row[i];
        if (r >= lo && r < hi) {
            int pos = row_ptr[r] + erank[i];
            ecol[pos] = col[i];
        }
    }
}

// pre-convert all 2L weight matrices to bf16, [o][k] row-major (= MFMA B layout)
__global__ __launch_bounds__(256) void wconv_kernel(const float* __restrict__ cw,
                                                    const float* __restrict__ hw,
                                                    unsigned short* __restrict__ wbt, int L) {
    int idx = blockIdx.x * blockDim.x + threadIdx.x;
    int total = 2 * L * 4096;
    if (idx >= total) return;
    int mat = idx >> 12;
    int rem = idx & 4095;
    const float* src = (mat < L) ? (cw + (size_t)mat * 4096) : (hw + (size_t)(mat - L) * 4096);
    wbt[idx] = f2b(src[rem]);
}

// ---------------- MFMA helpers ----------------
// A tile: s_a[node][k] bf16 stride WST; wave computes nodes wbase..wbase+15.
// B tile: s_b[o][k] bf16 stride WST. D layout: col=l16, row=quad*4+reg.

__device__ __forceinline__ void mfma_tile(const unsigned short* s_a,
                                          const unsigned short* s_b,
                                          int l16, int quad, int wbase, f32x4 acc[4]) {
    const unsigned short* ap = &s_a[(size_t)(wbase + l16) * WST + quad * 8];
    const unsigned short* bp = &s_b[(size_t)l16 * WST + quad * 8];
#pragma unroll
    for (int kt = 0; kt < 2; kt++) {
        bf16x8 a = *(const bf16x8*)(ap + kt * 32);
#pragma unroll
        for (int nt = 0; nt < 4; nt++) {
            bf16x8 b = *(const bf16x8*)(bp + (size_t)nt * 16 * WST + kt * 32);
            acc[nt] = __builtin_amdgcn_mfma_f32_16x16x32_bf16(a, b, acc[nt], 0, 0, 0);
        }
    }
}

// stage a pre-converted bf16 weight matrix (plain copy into padded LDS rows)
__device__ __forceinline__ void stage_wb(const unsigned short* __restrict__ wsrc,
                                         unsigned short* s_wb, int tid) {
    for (int i = tid; i < 512; i += 256) {
        int r = i >> 3, seg = i & 7;
        *(uint4*)(&s_wb[r * WST + seg * 8]) = ((const uint4*)(wsrc + r * 64))[seg];
    }
}

// ---------------- initial conv matmul: m = bf16(relu(x @ cw0^T)) ----------------

__global__ __launch_bounds__(256) void mm_relu_kernel(const float* __restrict__ h,
                                                      const unsigned short* __restrict__ wb,
                                                      __hip_bfloat16* __restrict__ m, int n) {
    __shared__ unsigned short s_hb[NPB * WST];
    __shared__ unsigned short s_wb[64 * WST];
    int tid = threadIdx.x;
    int base = blockIdx.x * NPB;
    stage_wb(wb, s_wb, tid);
    for (int i = tid; i < 512; i += 256) {
        int r = i >> 3, seg = i & 7;
        uint2 p = make_uint2(0u, 0u);
        if (base + r < n) {
            const float4* hp = (const float4*)(h + (size_t)(base + r) * HIDDEN + seg * 8);
            float4 ha = hp[0], hb = hp[1];
            p.x = (unsigned int)f2b(ha.x) | ((unsigned int)f2b(ha.y) << 16);
            p.y = (unsigned int)f2b(ha.z) | ((unsigned int)f2b(ha.w) << 16);
            unsigned int pz = (unsigned int)f2b(hb.x) | ((unsigned int)f2b(hb.y) << 16);
            unsigned int pw = (unsigned int)f2b(hb.z) | ((unsigned int)f2b(hb.w) << 16);
            *(uint4*)(&s_hb[r * WST + seg * 8]) = make_uint4(p.x, p.y, pz, pw);
        } else {
            *(uint4*)(&s_hb[r * WST + seg * 8]) = make_uint4(0u, 0u, 0u, 0u);
        }
    }
    __syncthreads();
    int lane = tid & 63, wave = tid >> 6;
    int quad = lane >> 4, l16 = lane & 15;
    int wbase = wave * 16;
    f32x4 acc[4];
    acc[0] = (f32x4){0.f,0.f,0.f,0.f}; acc[1] = (f32x4){0.f,0.f,0.f,0.f};
    acc[2] = (f32x4){0.f,0.f,0.f,0.f}; acc[3] = (f32x4){0.f,0.f,0.f,0.f};
    mfma_tile(s_hb, s_wb, l16, quad, wbase, acc);
    unsigned short* mo = (unsigned short*)m;
#pragma unroll
    for (int r = 0; r < 4; r++) {
        int node = base + wbase + quad * 4 + r;
        if (node < n) {
#pragma unroll
            for (int nt = 0; nt < 4; nt++)
                mo[(size_t)node * HIDDEN + nt * 16 + l16] = f2b(fmaxf(acc[nt][r], 0.f));
        }
    }
}

// ---------------- aggregation ----------------
// Two nodes per wave: lanes 0-31 -> node 2w, lanes 32-63 -> node 2w+1.
// Each lane owns 2 channels (float2/uint loads). 8-deep gather MLP per node
// = 16 gather instructions in flight per wave. Also emits bf16 h' for the
// GEMM kernel's A-tile staging.
__global__ __launch_bounds__(256) void aggregate_kernel(const float* __restrict__ h,
                                                        const __hip_bfloat16* __restrict__ m,
                                                        const int* __restrict__ row_ptr,
                                                        const int* __restrict__ ecol,
                                                        const float* __restrict__ nw,
                                                        float* __restrict__ out,
                                                        __hip_bfloat16* __restrict__ hb, int n) {
    int lane = threadIdx.x & 63;
    int wave = (blockIdx.x * blockDim.x + threadIdx.x) >> 6;
    int half = lane >> 5;
    int sl = lane & 31;
    int node = 2 * wave + half;
    if (node >= n) return;
    int beg = row_ptr[node];
    int end = row_ptr[node + 1];
    float2 s = *(const float2*)(h + (size_t)node * HIDDEN + 2 * sl);
    const unsigned short* mi = (const unsigned short*)m;
    float ax[8], ay[8];
#pragma unroll
    for (int q = 0; q < 8; q++) { ax[q] = 0.f; ay[q] = 0.f; }
    int sbase = half * 32;
    for (int b0 = beg; b0 < end; b0 += 32) {
        int idx = b0 + sl;
        int myc = ecol[idx < end ? idx : end - 1];
        int cnt = end - b0;
        if (cnt > 32) cnt = 32;
        for (int q0 = 0; q0 < cnt; q0 += 8) {
            int c[8];
#pragma unroll
            for (int j = 0; j < 8; j++) c[j] = __shfl(myc, sbase + q0 + j, 64);
            unsigned int u[8];
#pragma unroll
            for (int j = 0; j < 8; j++)
                u[j] = *(const unsigned int*)(mi + (size_t)c[j] * HIDDEN + 2 * sl);
#pragma unroll
            for (int j = 0; j < 8; j++) {
                bool ok = (q0 + j) < cnt;
                ax[j] += ok ? b2f((unsigned short)(u[j] & 0xffffu)) : 0.f;
                ay[j] += ok ? b2f((unsigned short)(u[j] >> 16)) : 0.f;
            }
        }
    }
    s.x += (((ax[0] + ax[1]) + (ax[2] + ax[3])) + ((ax[4] + ax[5]) + (ax[6] + ax[7])));
    s.y += (((ay[0] + ay[1]) + (ay[2] + ay[3])) + ((ay[4] + ay[5]) + (ay[6] + ay[7])));
    float ss = s.x * s.x + s.y * s.y;
#pragma unroll
    for (int off = 16; off > 0; off >>= 1) ss += __shfl_xor(ss, off, 64);
    float inv = rsqrtf(ss * (1.0f / 64.0f) + EPS);
    float2 w2 = *(const float2*)(nw + 2 * sl);
    float2 o2 = make_float2(s.x * inv * w2.x, s.y * inv * w2.y);
    *(float2*)(out + (size_t)node * HIDDEN + 2 * sl) = o2;
    unsigned int pb = (unsigned int)f2b(o2.x) | ((unsigned int)f2b(o2.y) << 16);
    *(unsigned int*)((unsigned short*)hb + (size_t)node * HIDDEN + 2 * sl) = pb;
}

// ---------------- fused hidden + next-conv kernel ----------------
// Phase B: h_new = rmsnorm(h' + relu(h' @ hw^T), hnw)  (A-tile from bf16 hb;
//          residual f32 from global, L2-hot). Phase C: m_out with next conv w.

__global__ __launch_bounds__(256) void hidden_next_kernel(float* __restrict__ h,
                                                          const __hip_bfloat16* __restrict__ hb,
                                                          const unsigned short* __restrict__ hwb,
                                                          const unsigned short* cwb_next,
                                                          const float* __restrict__ hnw,
                                                          __hip_bfloat16* m_out, int n) {
    __shared__ unsigned short s_hb[NPB * WST];
    __shared__ unsigned short s_wb[64 * WST];
    __shared__ unsigned short s_wb2[64 * WST];
    int tid = threadIdx.x;
    int base = blockIdx.x * NPB;
    stage_wb(hwb, s_wb, tid);
    if (cwb_next) stage_wb(cwb_next, s_wb2, tid);
    const unsigned short* hbs = (const unsigned short*)hb;
    for (int i = tid; i < 512; i += 256) {
        int r = i >> 3, seg = i & 7;
        uint4 p = make_uint4(0u, 0u, 0u, 0u);
        if (base + r < n) p = ((const uint4*)(hbs + (size_t)(base + r) * HIDDEN))[seg];
        *(uint4*)(&s_hb[r * WST + seg * 8]) = p;
    }
    __syncthreads();

    int lane = tid & 63, wave = tid >> 6;
    int quad = lane >> 4, l16 = lane & 15;
    int wbase = wave * 16;

    // ---- Phase B ----
    f32x4 acc[4];
    acc[0] = (f32x4){0.f,0.f,0.f,0.f}; acc[1] = (f32x4){0.f,0.f,0.f,0.f};
    acc[2] = (f32x4){0.f,0.f,0.f,0.f}; acc[3] = (f32x4){0.f,0.f,0.f,0.f};
    mfma_tile(s_hb, s_wb, l16, quad, wbase, acc);

    float hv[4][4];
    float ssq[4] = {0.f, 0.f, 0.f, 0.f};
#pragma unroll
    for (int r = 0; r < 4; r++) {
        int node = base + wbase + quad * 4 + r;
        bool ok = node < n;
#pragma unroll
        for (int nt = 0; nt < 4; nt++) {
            float hres = ok ? h[(size_t)node * HIDDEN + nt * 16 + l16] : 0.f;
            float v = hres + fmaxf(acc[nt][r], 0.f);
            hv[r][nt] = v;
            ssq[r] += v * v;
        }
    }
#pragma unroll
    for (int mk = 1; mk <= 8; mk <<= 1) {
#pragma unroll
        for (int r = 0; r < 4; r++) ssq[r] += __shfl_xor(ssq[r], mk, 64);
    }
    float nwv[4];
#pragma unroll
    for (int nt = 0; nt < 4; nt++) nwv[nt] = hnw[nt * 16 + l16];
#pragma unroll
    for (int r = 0; r < 4; r++) {
        float inv = rsqrtf(ssq[r] * (1.0f / 64.0f) + EPS);
#pragma unroll
        for (int nt = 0; nt < 4; nt++) hv[r][nt] *= inv * nwv[nt];
    }
#pragma unroll
    for (int r = 0; r < 4; r++) {
        int node = base + wbase + quad * 4 + r;
        if (node < n) {
#pragma unroll
            for (int nt = 0; nt < 4; nt++)
                h[(size_t)node * HIDDEN + nt * 16 + l16] = hv[r][nt];
        }
    }

    if (!m_out) return;

    // ---- D -> A layout (own rows only; intra-wave, no barrier) ----
#pragma unroll
    for (int r = 0; r < 4; r++) {
        int nl = wbase + quad * 4 + r;
#pragma unroll
        for (int nt = 0; nt < 4; nt++)
            s_hb[nl * WST + nt * 16 + l16] = f2b(hv[r][nt]);
    }

    // ---- Phase C ----
    f32x4 acc2[4];
    acc2[0] = (f32x4){0.f,0.f,0.f,0.f}; acc2[1] = (f32x4){0.f,0.f,0.f,0.f};
    acc2[2] = (f32x4){0.f,0.f,0.f,0.f}; acc2[3] = (f32x4){0.f,0.f,0.f,0.f};
    mfma_tile(s_hb, s_wb2, l16, quad, wbase, acc2);
    unsigned short* mo = (unsigned short*)m_out;
#pragma unroll
    for (int r = 0; r < 4; r++) {
        int node = base + wbase + quad * 4 + r;
        if (node < n) {
#pragma unroll
            for (int nt = 0; nt < 4; nt++)
                mo[(size_t)node * HIDDEN + nt * 16 + l16] = f2b(fmaxf(acc2[nt][r], 0.f));
        }
    }
}

// ---------------- launch ----------------

static inline size_t align_up(size_t x, size_t a) { return (x + a - 1) & ~(a - 1); }

extern "C" void kernel_launch(void* const* d_in, const int* in_sizes, int n_in,
                              void* d_out, int out_size, void* d_ws, size_t ws_size,
                              hipStream_t stream) {
    const float* x       = (const float*)d_in[0];
    const float* conv_w  = (const float*)d_in[1];
    const float* conv_nw = (const float*)d_in[2];
    const float* hid_w   = (const float*)d_in[3];
    const float* hid_nw  = (const float*)d_in[4];
    const int*   row     = (const int*)d_in[5];
    const int*   col     = (const int*)d_in[6];
    float* out = (float*)d_out;

    const int n = in_sizes[0] / HIDDEN;   // 100000
    const int e = in_sizes[5];            // 800000
    const int L = in_sizes[1] / 4096;     // 4

    // workspace layout
    size_t off = 0;
    char* ws = (char*)d_ws;
    __hip_bfloat16* mA = (__hip_bfloat16*)(ws + off); off = align_up(off + (size_t)n * HIDDEN * 2, 16);
    __hip_bfloat16* mB = (__hip_bfloat16*)(ws + off); off = align_up(off + (size_t)n * HIDDEN * 2, 16);
    __hip_bfloat16* hbb = (__hip_bfloat16*)(ws + off); off = align_up(off + (size_t)n * HIDDEN * 2, 16);
    unsigned short* wbt = (unsigned short*)(ws + off); off = align_up(off + (size_t)2 * L * 4096 * 2, 16);
    int* row_ptr = (int*)(ws + off);           off = align_up(off + (size_t)(n + 1) * 4, 16);
    int* cnt = (int*)(ws + off);               off = align_up(off + (size_t)n * 4, 16);
    int* bsum = (int*)(ws + off);              off = align_up(off + (size_t)1024 * 4, 16);
    int* erank = (int*)(ws + off);             off = align_up(off + (size_t)e * 4, 16);
    int* ecol = (int*)(ws + off);              off = align_up(off + (size_t)e * 4, 16);

    const int nb = (n + 255) / 256;

    // CSR build (once per launch; edges constant across layers)
    hipMemsetAsync(cnt, 0, (size_t)n * 4, stream);
    hist_rank_kernel<<<1024, 256, 0, stream>>>(row, cnt, erank, e);
    block_sum_kernel<<<nb, 256, 0, stream>>>(cnt, bsum, n);
    scan_bsum_kernel<<<1, 1024, 0, stream>>>(bsum, nb, row_ptr + n);
    scan_final_kernel<<<nb, 256, 0, stream>>>(cnt, bsum, row_ptr, n);
    fill_kernel<<<1024, 256, 0, stream>>>(row, col, row_ptr, erank, ecol, e, n);

    // weights -> bf16 once
    wconv_kernel<<<(2 * L * 4096 + 255) / 256, 256, 0, stream>>>(conv_w, hid_w, wbt, L);

    const int blocks = (n + NPB - 1) / NPB;
    const int agg_blocks = ((n + 1) / 2 * 64 + 255) / 256;   // two nodes per wave

    // initial conv matmul for layer 0
    mm_relu_kernel<<<blocks, 256, 0, stream>>>(x, wbt, mA, n);

    const __hip_bfloat16* mi = mA;
    __hip_bfloat16* mo = mB;
    const float* hcur = x;
    for (int l = 0; l < L; l++) {
        aggregate_kernel<<<agg_blocks, 256, 0, stream>>>(hcur, mi, row_ptr, ecol,
                                                         conv_nw + (size_t)l * HIDDEN, out, hbb, n);
        hidden_next_kernel<<<blocks, 256, 0, stream>>>(
            out, hbb, wbt + (size_t)(L + l) * 4096,
            (l < L - 1) ? (wbt + (size_t)(l + 1) * 4096) : nullptr,
            hid_nw + (size_t)l * HIDDEN,
            (l < L - 1) ? mo : nullptr, n);
        __hip_bfloat16* tmp = (__hip_bfloat16*)mi; mi = mo; mo = tmp;
        hcur = out;
    }
}

// Round 9
// 291.145 us; speedup vs baseline: 1.7470x; 1.0860x over previous
//
#include <hip/hip_runtime.h>
#include <hip/hip_bf16.h>

#define HIDDEN 64
#define EPS 1e-5f
#define NPB 64            // nodes per block in GEMM kernels
#define WST 72            // bf16 LDS row stride (shorts): 16B-aligned, breaks 128B aliasing

typedef __attribute__((ext_vector_type(8))) short bf16x8;   // MFMA A/B frag (4 VGPRs)
typedef __attribute__((ext_vector_type(4))) float f32x4;    // MFMA C/D frag

__device__ __forceinline__ unsigned short f2b(float x) {
    __hip_bfloat16 b = __float2bfloat16(x);
    return *(unsigned short*)&b;
}
__device__ __forceinline__ float b2f(unsigned short u) {
    unsigned int ui = (unsigned int)u << 16;
    return *(float*)&ui;
}

// ---------------- CSR build ----------------

__global__ __launch_bounds__(256) void hist_rank_kernel(const int* __restrict__ row,
                                                        int* __restrict__ cnt,
                                                        int* __restrict__ erank, int e) {
    int stride = gridDim.x * blockDim.x;
    for (int i = blockIdx.x * blockDim.x + threadIdx.x; i < e; i += stride) {
        int r = row[i];
        erank[i] = atomicAdd(&cnt[r], 1);
    }
}

__global__ __launch_bounds__(256) void block_sum_kernel(const int* __restrict__ cnt,
                                                        int* __restrict__ bsum, int n) {
    __shared__ int wsum[4];
    int tid = threadIdx.x;
    int i = blockIdx.x * 256 + tid;
    int v = (i < n) ? cnt[i] : 0;
#pragma unroll
    for (int off = 32; off > 0; off >>= 1) v += __shfl_xor(v, off, 64);
    if ((tid & 63) == 0) wsum[tid >> 6] = v;
    __syncthreads();
    if (tid == 0) bsum[blockIdx.x] = wsum[0] + wsum[1] + wsum[2] + wsum[3];
}

__global__ __launch_bounds__(1024) void scan_bsum_kernel(int* __restrict__ bsum, int nb,
                                                         int* __restrict__ total_out) {
    __shared__ int wsum[16];
    __shared__ int wexcl[16];
    int tid = threadIdx.x;
    int lane = tid & 63;
    int w = tid >> 6;
    int v = (tid < nb) ? bsum[tid] : 0;
    int sc = v;
#pragma unroll
    for (int off = 1; off < 64; off <<= 1) {
        int t = __shfl_up(sc, off, 64);
        if (lane >= off) sc += t;
    }
    if (lane == 63) wsum[w] = sc;
    __syncthreads();
    if (tid == 0) {
        int a = 0;
#pragma unroll
        for (int j = 0; j < 16; j++) { wexcl[j] = a; a += wsum[j]; }
        *total_out = a;
    }
    __syncthreads();
    if (tid < nb) bsum[tid] = wexcl[w] + (sc - v);
}

__global__ __launch_bounds__(256) void scan_final_kernel(const int* __restrict__ cnt,
                                                         const int* __restrict__ bexcl,
                                                         int* __restrict__ row_ptr, int n) {
    __shared__ int wsum[4];
    __shared__ int wexcl[4];
    int tid = threadIdx.x;
    int lane = tid & 63;
    int w = tid >> 6;
    int i = blockIdx.x * 256 + tid;
    int v = (i < n) ? cnt[i] : 0;
    int sc = v;
#pragma unroll
    for (int off = 1; off < 64; off <<= 1) {
        int t = __shfl_up(sc, off, 64);
        if (lane >= off) sc += t;
    }
    if (lane == 63) wsum[w] = sc;
    __syncthreads();
    if (tid == 0) {
        int a = 0;
#pragma unroll
        for (int j = 0; j < 4; j++) { wexcl[j] = a; a += wsum[j]; }
    }
    __syncthreads();
    if (i < n) row_ptr[i] = bexcl[blockIdx.x] + wexcl[w] + (sc - v);
}

__global__ __launch_bounds__(256) void fill_kernel(const int* __restrict__ row,
                                                   const int* __restrict__ col,
                                                   const int* __restrict__ row_ptr,
                                                   const int* __restrict__ erank,
                                                   int* __restrict__ ecol, int e, int n) {
    int cls = blockIdx.x & 7;
    int sub = blockIdx.x >> 3;
    int nsub = gridDim.x >> 3;
    int lo = (int)(((long long)n * cls) >> 3);
    int hi = (int)(((long long)n * (cls + 1)) >> 3);
    for (int i = sub * 256 + threadIdx.x; i < e; i += nsub * 256) {
        int r = row[i];
        if (r >= lo && r < hi) {
            int pos = row_ptr[r] + erank[i];
            ecol[pos] = col[i];
        }
    }
}

// pre-convert all 2L weight matrices to bf16, [o][k] row-major (= MFMA B layout)
__global__ __launch_bounds__(256) void wconv_kernel(const float* __restrict__ cw,
                                                    const float* __restrict__ hw,
                                                    unsigned short* __restrict__ wbt, int L) {
    int idx = blockIdx.x * blockDim.x + threadIdx.x;
    int total = 2 * L * 4096;
    if (idx >= total) return;
    int mat = idx >> 12;
    int rem = idx & 4095;
    const float* src = (mat < L) ? (cw + (size_t)mat * 4096) : (hw + (size_t)(mat - L) * 4096);
    wbt[idx] = f2b(src[rem]);
}

// ---------------- MFMA helpers ----------------
// A tile: s_a[node][k] bf16 stride WST; wave computes nodes wbase..wbase+15.
// B tile: s_b[o][k] bf16 stride WST. D layout: col=l16, row=quad*4+reg.

__device__ __forceinline__ void mfma_tile(const unsigned short* s_a,
                                          const unsigned short* s_b,
                                          int l16, int quad, int wbase, f32x4 acc[4]) {
    const unsigned short* ap = &s_a[(size_t)(wbase + l16) * WST + quad * 8];
    const unsigned short* bp = &s_b[(size_t)l16 * WST + quad * 8];
#pragma unroll
    for (int kt = 0; kt < 2; kt++) {
        bf16x8 a = *(const bf16x8*)(ap + kt * 32);
#pragma unroll
        for (int nt = 0; nt < 4; nt++) {
            bf16x8 b = *(const bf16x8*)(bp + (size_t)nt * 16 * WST + kt * 32);
            acc[nt] = __builtin_amdgcn_mfma_f32_16x16x32_bf16(a, b, acc[nt], 0, 0, 0);
        }
    }
}

// stage a pre-converted bf16 weight matrix (plain copy into padded LDS rows)
__device__ __forceinline__ void stage_wb(const unsigned short* __restrict__ wsrc,
                                         unsigned short* s_wb, int tid) {
    for (int i = tid; i < 512; i += 256) {
        int r = i >> 3, seg = i & 7;
        *(uint4*)(&s_wb[r * WST + seg * 8]) = ((const uint4*)(wsrc + r * 64))[seg];
    }
}

// ---------------- initial conv matmul: m = bf16(relu(x @ cw0^T)) ----------------

__global__ __launch_bounds__(256) void mm_relu_kernel(const float* __restrict__ h,
                                                      const unsigned short* __restrict__ wb,
                                                      __hip_bfloat16* __restrict__ m, int n) {
    __shared__ unsigned short s_hb[NPB * WST];
    __shared__ unsigned short s_wb[64 * WST];
    int tid = threadIdx.x;
    int base = blockIdx.x * NPB;
    stage_wb(wb, s_wb, tid);
    for (int i = tid; i < 512; i += 256) {
        int r = i >> 3, seg = i & 7;
        if (base + r < n) {
            const float4* hp = (const float4*)(h + (size_t)(base + r) * HIDDEN + seg * 8);
            float4 ha = hp[0], hb = hp[1];
            uint4 p;
            p.x = (unsigned int)f2b(ha.x) | ((unsigned int)f2b(ha.y) << 16);
            p.y = (unsigned int)f2b(ha.z) | ((unsigned int)f2b(ha.w) << 16);
            p.z = (unsigned int)f2b(hb.x) | ((unsigned int)f2b(hb.y) << 16);
            p.w = (unsigned int)f2b(hb.z) | ((unsigned int)f2b(hb.w) << 16);
            *(uint4*)(&s_hb[r * WST + seg * 8]) = p;
        } else {
            *(uint4*)(&s_hb[r * WST + seg * 8]) = make_uint4(0u, 0u, 0u, 0u);
        }
    }
    __syncthreads();
    int lane = tid & 63, wave = tid >> 6;
    int quad = lane >> 4, l16 = lane & 15;
    int wbase = wave * 16;
    f32x4 acc[4];
    acc[0] = (f32x4){0.f,0.f,0.f,0.f}; acc[1] = (f32x4){0.f,0.f,0.f,0.f};
    acc[2] = (f32x4){0.f,0.f,0.f,0.f}; acc[3] = (f32x4){0.f,0.f,0.f,0.f};
    mfma_tile(s_hb, s_wb, l16, quad, wbase, acc);
    unsigned short* mo = (unsigned short*)m;
#pragma unroll
    for (int r = 0; r < 4; r++) {
        int node = base + wbase + quad * 4 + r;
        if (node < n) {
#pragma unroll
            for (int nt = 0; nt < 4; nt++)
                mo[(size_t)node * HIDDEN + nt * 16 + l16] = f2b(fmaxf(acc[nt][r], 0.f));
        }
    }
}

// ---------------- aggregation ----------------
// Four nodes per wave: group g = lane>>4 handles node 4w+g; lane owns 4
// channels (uint2 8B gathers; 16 lanes x 8B = one full m row per edge).
// 8-deep unrolled gather MLP covers 4 edges per load instruction.
// Residual h from f32 x (layer 0) or bf16 h buffer. Output h' bf16 only.
__global__ __launch_bounds__(256) void aggregate_kernel(const float* hf,
                                                        const __hip_bfloat16* hb_in,
                                                        const __hip_bfloat16* __restrict__ m,
                                                        const int* __restrict__ row_ptr,
                                                        const int* __restrict__ ecol,
                                                        const float* __restrict__ nw,
                                                        __hip_bfloat16* __restrict__ hb_out,
                                                        int n) {
    int lane = threadIdx.x & 63;
    int wave = (blockIdx.x * blockDim.x + threadIdx.x) >> 6;
    int grp = lane >> 4;
    int sl = lane & 15;
    int node = 4 * wave + grp;
    if (node >= n) return;
    int beg = row_ptr[node];
    int end = row_ptr[node + 1];
    float s0, s1, s2, s3;
    if (hf) {
        float4 v = *(const float4*)(hf + (size_t)node * HIDDEN + 4 * sl);
        s0 = v.x; s1 = v.y; s2 = v.z; s3 = v.w;
    } else {
        uint2 u = *(const uint2*)((const unsigned short*)hb_in + (size_t)node * HIDDEN + 4 * sl);
        s0 = b2f((unsigned short)(u.x & 0xffffu)); s1 = b2f((unsigned short)(u.x >> 16));
        s2 = b2f((unsigned short)(u.y & 0xffffu)); s3 = b2f((unsigned short)(u.y >> 16));
    }
    const unsigned short* mi = (const unsigned short*)m;
    float a0[8], a1[8], a2[8], a3[8];
#pragma unroll
    for (int q = 0; q < 8; q++) { a0[q] = 0.f; a1[q] = 0.f; a2[q] = 0.f; a3[q] = 0.f; }
    int sbase = grp * 16;
    for (int b0 = beg; b0 < end; b0 += 16) {
        int idx = b0 + sl;
        int myc = ecol[idx < end ? idx : end - 1];
        int cnt = end - b0;
        if (cnt > 16) cnt = 16;
        for (int q0 = 0; q0 < cnt; q0 += 8) {
            int c[8];
#pragma unroll
            for (int j = 0; j < 8; j++) c[j] = __shfl(myc, sbase + q0 + j, 64);
            uint2 u[8];
#pragma unroll
            for (int j = 0; j < 8; j++)
                u[j] = *(const uint2*)(mi + (size_t)c[j] * HIDDEN + 4 * sl);
#pragma unroll
            for (int j = 0; j < 8; j++) {
                bool ok = (q0 + j) < cnt;
                a0[j] += ok ? b2f((unsigned short)(u[j].x & 0xffffu)) : 0.f;
                a1[j] += ok ? b2f((unsigned short)(u[j].x >> 16)) : 0.f;
                a2[j] += ok ? b2f((unsigned short)(u[j].y & 0xffffu)) : 0.f;
                a3[j] += ok ? b2f((unsigned short)(u[j].y >> 16)) : 0.f;
            }
        }
    }
    s0 += (((a0[0] + a0[1]) + (a0[2] + a0[3])) + ((a0[4] + a0[5]) + (a0[6] + a0[7])));
    s1 += (((a1[0] + a1[1]) + (a1[2] + a1[3])) + ((a1[4] + a1[5]) + (a1[6] + a1[7])));
    s2 += (((a2[0] + a2[1]) + (a2[2] + a2[3])) + ((a2[4] + a2[5]) + (a2[6] + a2[7])));
    s3 += (((a3[0] + a3[1]) + (a3[2] + a3[3])) + ((a3[4] + a3[5]) + (a3[6] + a3[7])));
    float ss = s0 * s0 + s1 * s1 + s2 * s2 + s3 * s3;
#pragma unroll
    for (int off = 8; off > 0; off >>= 1) ss += __shfl_xor(ss, off, 64);
    float inv = rsqrtf(ss * (1.0f / 64.0f) + EPS);
    float4 w4 = *(const float4*)(nw + 4 * sl);
    uint2 pb;
    pb.x = (unsigned int)f2b(s0 * inv * w4.x) | ((unsigned int)f2b(s1 * inv * w4.y) << 16);
    pb.y = (unsigned int)f2b(s2 * inv * w4.z) | ((unsigned int)f2b(s3 * inv * w4.w) << 16);
    *(uint2*)((unsigned short*)hb_out + (size_t)node * HIDDEN + 4 * sl) = pb;
}

// ---------------- fused hidden + next-conv kernel ----------------
// Phase B: h_new = rmsnorm(h' + relu(h' @ hw^T), hnw); residual taken from the
// bf16 LDS A-tile (no global residual traffic). Output: f32 d_out on last
// layer, bf16 h buffer otherwise. Phase C: m_out = bf16(relu(h_new @ cw_next^T)).

__global__ __launch_bounds__(256) void hidden_next_kernel(const __hip_bfloat16* __restrict__ hb_in,
                                                          const unsigned short* __restrict__ hwb,
                                                          const unsigned short* cwb_next,
                                                          const float* __restrict__ hnw,
                                                          float* out_f32,
                                                          __hip_bfloat16* hb_new,
                                                          __hip_bfloat16* m_out, int n) {
    __shared__ unsigned short s_hb[NPB * WST];
    __shared__ unsigned short s_wb[64 * WST];
    __shared__ unsigned short s_wb2[64 * WST];
    int tid = threadIdx.x;
    int base = blockIdx.x * NPB;
    stage_wb(hwb, s_wb, tid);
    if (cwb_next) stage_wb(cwb_next, s_wb2, tid);
    const unsigned short* hbs = (const unsigned short*)hb_in;
    for (int i = tid; i < 512; i += 256) {
        int r = i >> 3, seg = i & 7;
        uint4 p = make_uint4(0u, 0u, 0u, 0u);
        if (base + r < n) p = ((const uint4*)(hbs + (size_t)(base + r) * HIDDEN))[seg];
        *(uint4*)(&s_hb[r * WST + seg * 8]) = p;
    }
    __syncthreads();

    int lane = tid & 63, wave = tid >> 6;
    int quad = lane >> 4, l16 = lane & 15;
    int wbase = wave * 16;

    // ---- Phase B ----
    f32x4 acc[4];
    acc[0] = (f32x4){0.f,0.f,0.f,0.f}; acc[1] = (f32x4){0.f,0.f,0.f,0.f};
    acc[2] = (f32x4){0.f,0.f,0.f,0.f}; acc[3] = (f32x4){0.f,0.f,0.f,0.f};
    mfma_tile(s_hb, s_wb, l16, quad, wbase, acc);

    float hv[4][4];
    float ssq[4] = {0.f, 0.f, 0.f, 0.f};
#pragma unroll
    for (int r = 0; r < 4; r++) {
        int nl = wbase + quad * 4 + r;
#pragma unroll
        for (int nt = 0; nt < 4; nt++) {
            float hres = b2f(s_hb[(size_t)nl * WST + nt * 16 + l16]);
            float v = hres + fmaxf(acc[nt][r], 0.f);
            hv[r][nt] = v;
            ssq[r] += v * v;
        }
    }
#pragma unroll
    for (int mk = 1; mk <= 8; mk <<= 1) {
#pragma unroll
        for (int r = 0; r < 4; r++) ssq[r] += __shfl_xor(ssq[r], mk, 64);
    }
    float nwv[4];
#pragma unroll
    for (int nt = 0; nt < 4; nt++) nwv[nt] = hnw[nt * 16 + l16];
#pragma unroll
    for (int r = 0; r < 4; r++) {
        float inv = rsqrtf(ssq[r] * (1.0f / 64.0f) + EPS);
#pragma unroll
        for (int nt = 0; nt < 4; nt++) hv[r][nt] *= inv * nwv[nt];
    }
    if (out_f32) {
#pragma unroll
        for (int r = 0; r < 4; r++) {
            int node = base + wbase + quad * 4 + r;
            if (node < n) {
#pragma unroll
                for (int nt = 0; nt < 4; nt++)
                    out_f32[(size_t)node * HIDDEN + nt * 16 + l16] = hv[r][nt];
            }
        }
    }
    if (hb_new) {
        unsigned short* ho = (unsigned short*)hb_new;
#pragma unroll
        for (int r = 0; r < 4; r++) {
            int node = base + wbase + quad * 4 + r;
            if (node < n) {
#pragma unroll
                for (int nt = 0; nt < 4; nt++)
                    ho[(size_t)node * HIDDEN + nt * 16 + l16] = f2b(hv[r][nt]);
            }
        }
    }

    if (!m_out) return;

    // ---- D -> A layout (own rows only; intra-wave, no barrier) ----
#pragma unroll
    for (int r = 0; r < 4; r++) {
        int nl = wbase + quad * 4 + r;
#pragma unroll
        for (int nt = 0; nt < 4; nt++)
            s_hb[(size_t)nl * WST + nt * 16 + l16] = f2b(hv[r][nt]);
    }

    // ---- Phase C ----
    f32x4 acc2[4];
    acc2[0] = (f32x4){0.f,0.f,0.f,0.f}; acc2[1] = (f32x4){0.f,0.f,0.f,0.f};
    acc2[2] = (f32x4){0.f,0.f,0.f,0.f}; acc2[3] = (f32x4){0.f,0.f,0.f,0.f};
    mfma_tile(s_hb, s_wb2, l16, quad, wbase, acc2);
    unsigned short* mo = (unsigned short*)m_out;
#pragma unroll
    for (int r = 0; r < 4; r++) {
        int node = base + wbase + quad * 4 + r;
        if (node < n) {
#pragma unroll
            for (int nt = 0; nt < 4; nt++)
                mo[(size_t)node * HIDDEN + nt * 16 + l16] = f2b(fmaxf(acc2[nt][r], 0.f));
        }
    }
}

// ---------------- launch ----------------

static inline size_t align_up(size_t x, size_t a) { return (x + a - 1) & ~(a - 1); }

extern "C" void kernel_launch(void* const* d_in, const int* in_sizes, int n_in,
                              void* d_out, int out_size, void* d_ws, size_t ws_size,
                              hipStream_t stream) {
    const float* x       = (const float*)d_in[0];
    const float* conv_w  = (const float*)d_in[1];
    const float* conv_nw = (const float*)d_in[2];
    const float* hid_w   = (const float*)d_in[3];
    const float* hid_nw  = (const float*)d_in[4];
    const int*   row     = (const int*)d_in[5];
    const int*   col     = (const int*)d_in[6];
    float* out = (float*)d_out;

    const int n = in_sizes[0] / HIDDEN;   // 100000
    const int e = in_sizes[5];            // 800000
    const int L = in_sizes[1] / 4096;     // 4

    // workspace layout
    size_t off = 0;
    char* ws = (char*)d_ws;
    __hip_bfloat16* mA = (__hip_bfloat16*)(ws + off);  off = align_up(off + (size_t)n * HIDDEN * 2, 16);
    __hip_bfloat16* mB = (__hip_bfloat16*)(ws + off);  off = align_up(off + (size_t)n * HIDDEN * 2, 16);
    __hip_bfloat16* hb1 = (__hip_bfloat16*)(ws + off); off = align_up(off + (size_t)n * HIDDEN * 2, 16);
    __hip_bfloat16* hb2 = (__hip_bfloat16*)(ws + off); off = align_up(off + (size_t)n * HIDDEN * 2, 16);
    unsigned short* wbt = (unsigned short*)(ws + off); off = align_up(off + (size_t)2 * L * 4096 * 2, 16);
    int* row_ptr = (int*)(ws + off);           off = align_up(off + (size_t)(n + 1) * 4, 16);
    int* cnt = (int*)(ws + off);               off = align_up(off + (size_t)n * 4, 16);
    int* bsum = (int*)(ws + off);              off = align_up(off + (size_t)1024 * 4, 16);
    int* erank = (int*)(ws + off);             off = align_up(off + (size_t)e * 4, 16);
    int* ecol = (int*)(ws + off);              off = align_up(off + (size_t)e * 4, 16);

    const int nb = (n + 255) / 256;

    // CSR build (once per launch; edges constant across layers)
    hipMemsetAsync(cnt, 0, (size_t)n * 4, stream);
    hist_rank_kernel<<<1024, 256, 0, stream>>>(row, cnt, erank, e);
    block_sum_kernel<<<nb, 256, 0, stream>>>(cnt, bsum, n);
    scan_bsum_kernel<<<1, 1024, 0, stream>>>(bsum, nb, row_ptr + n);
    scan_final_kernel<<<nb, 256, 0, stream>>>(cnt, bsum, row_ptr, n);
    fill_kernel<<<1024, 256, 0, stream>>>(row, col, row_ptr, erank, ecol, e, n);

    // weights -> bf16 once
    wconv_kernel<<<(2 * L * 4096 + 255) / 256, 256, 0, stream>>>(conv_w, hid_w, wbt, L);

    const int blocks = (n + NPB - 1) / NPB;
    const int agg_blocks = ((n + 3) / 4 * 64 + 255) / 256;   // four nodes per wave

    // initial conv matmul for layer 0
    mm_relu_kernel<<<blocks, 256, 0, stream>>>(x, wbt, mA, n);

    const __hip_bfloat16* mi = mA;
    __hip_bfloat16* mo = mB;
    for (int l = 0; l < L; l++) {
        aggregate_kernel<<<agg_blocks, 256, 0, stream>>>(
            (l == 0) ? x : nullptr, (l == 0) ? nullptr : hb2, mi, row_ptr, ecol,
            conv_nw + (size_t)l * HIDDEN, hb1, n);
        bool last = (l == L - 1);
        hidden_next_kernel<<<blocks, 256, 0, stream>>>(
            hb1, wbt + (size_t)(L + l) * 4096,
            last ? nullptr : (wbt + (size_t)(l + 1) * 4096),
            hid_nw + (size_t)l * HIDDEN,
            last ? out : nullptr,
            last ? nullptr : hb2,
            last ? nullptr : mo, n);
        __hip_bfloat16* tmp = (__hip_bfloat16*)mi; mi = mo; mo = tmp;
    }
}

// Round 10
// 285.833 us; speedup vs baseline: 1.7795x; 1.0186x over previous
//
#include <hip/hip_runtime.h>
#include <hip/hip_bf16.h>

#define HIDDEN 64
#define EPS 1e-5f
#define NPB 64            // nodes per block, mm_relu
#define NPB2 128          // nodes per block, hidden_next (2 tiles/wave)
#define WST 72            // bf16 LDS row stride (shorts): 16B-aligned, breaks 128B aliasing

typedef __attribute__((ext_vector_type(8))) short bf16x8;   // MFMA A/B frag (4 VGPRs)
typedef __attribute__((ext_vector_type(4))) float f32x4;    // MFMA C/D frag

__device__ __forceinline__ unsigned short f2b(float x) {
    __hip_bfloat16 b = __float2bfloat16(x);
    return *(unsigned short*)&b;
}
__device__ __forceinline__ float b2f(unsigned short u) {
    unsigned int ui = (unsigned int)u << 16;
    return *(float*)&ui;
}
__device__ __forceinline__ float b2f_lo(unsigned int u) { unsigned int ui = u << 16; return *(float*)&ui; }
__device__ __forceinline__ float b2f_hi(unsigned int u) { unsigned int ui = u & 0xffff0000u; return *(float*)&ui; }

// ---------------- CSR build ----------------

__global__ __launch_bounds__(256) void hist_rank_kernel(const int* __restrict__ row,
                                                        int* __restrict__ cnt,
                                                        int* __restrict__ erank, int e) {
    int stride = gridDim.x * blockDim.x;
    for (int i = blockIdx.x * blockDim.x + threadIdx.x; i < e; i += stride) {
        int r = row[i];
        erank[i] = atomicAdd(&cnt[r], 1);
    }
}

__global__ __launch_bounds__(256) void block_sum_kernel(const int* __restrict__ cnt,
                                                        int* __restrict__ bsum, int n) {
    __shared__ int wsum[4];
    int tid = threadIdx.x;
    int i = blockIdx.x * 256 + tid;
    int v = (i < n) ? cnt[i] : 0;
#pragma unroll
    for (int off = 32; off > 0; off >>= 1) v += __shfl_xor(v, off, 64);
    if ((tid & 63) == 0) wsum[tid >> 6] = v;
    __syncthreads();
    if (tid == 0) bsum[blockIdx.x] = wsum[0] + wsum[1] + wsum[2] + wsum[3];
}

__global__ __launch_bounds__(1024) void scan_bsum_kernel(int* __restrict__ bsum, int nb,
                                                         int* __restrict__ total_out) {
    __shared__ int wsum[16];
    __shared__ int wexcl[16];
    int tid = threadIdx.x;
    int lane = tid & 63;
    int w = tid >> 6;
    int v = (tid < nb) ? bsum[tid] : 0;
    int sc = v;
#pragma unroll
    for (int off = 1; off < 64; off <<= 1) {
        int t = __shfl_up(sc, off, 64);
        if (lane >= off) sc += t;
    }
    if (lane == 63) wsum[w] = sc;
    __syncthreads();
    if (tid == 0) {
        int a = 0;
#pragma unroll
        for (int j = 0; j < 16; j++) { wexcl[j] = a; a += wsum[j]; }
        *total_out = a;
    }
    __syncthreads();
    if (tid < nb) bsum[tid] = wexcl[w] + (sc - v);
}

__global__ __launch_bounds__(256) void scan_final_kernel(const int* __restrict__ cnt,
                                                         const int* __restrict__ bexcl,
                                                         int* __restrict__ row_ptr, int n) {
    __shared__ int wsum[4];
    __shared__ int wexcl[4];
    int tid = threadIdx.x;
    int lane = tid & 63;
    int w = tid >> 6;
    int i = blockIdx.x * 256 + tid;
    int v = (i < n) ? cnt[i] : 0;
    int sc = v;
#pragma unroll
    for (int off = 1; off < 64; off <<= 1) {
        int t = __shfl_up(sc, off, 64);
        if (lane >= off) sc += t;
    }
    if (lane == 63) wsum[w] = sc;
    __syncthreads();
    if (tid == 0) {
        int a = 0;
#pragma unroll
        for (int j = 0; j < 4; j++) { wexcl[j] = a; a += wsum[j]; }
    }
    __syncthreads();
    if (i < n) row_ptr[i] = bexcl[blockIdx.x] + wexcl[w] + (sc - v);
}

__global__ __launch_bounds__(256) void fill_kernel(const int* __restrict__ row,
                                                   const int* __restrict__ col,
                                                   const int* __restrict__ row_ptr,
                                                   const int* __restrict__ erank,
                                                   int* __restrict__ ecol, int e, int n) {
    int cls = blockIdx.x & 7;
    int sub = blockIdx.x >> 3;
    int nsub = gridDim.x >> 3;
    int lo = (int)(((long long)n * cls) >> 3);
    int hi = (int)(((long long)n * (cls + 1)) >> 3);
    for (int i = sub * 256 + threadIdx.x; i < e; i += nsub * 256) {
        int r = row[i];
        if (r >= lo && r < hi) {
            int pos = row_ptr[r] + erank[i];
            ecol[pos] = col[i];
        }
    }
}

// pre-convert all 2L weight matrices to bf16, [o][k] row-major (= MFMA B layout)
__global__ __launch_bounds__(256) void wconv_kernel(const float* __restrict__ cw,
                                                    const float* __restrict__ hw,
                                                    unsigned short* __restrict__ wbt, int L) {
    int idx = blockIdx.x * blockDim.x + threadIdx.x;
    int total = 2 * L * 4096;
    if (idx >= total) return;
    int mat = idx >> 12;
    int rem = idx & 4095;
    const float* src = (mat < L) ? (cw + (size_t)mat * 4096) : (hw + (size_t)(mat - L) * 4096);
    wbt[idx] = f2b(src[rem]);
}

// ---------------- MFMA helpers ----------------
// A tile: s_a[node][k] bf16 stride WST; wave computes nodes wbase..wbase+15.
// B tile: s_b[o][k] bf16 stride WST. D layout: col=l16, row=quad*4+reg.

__device__ __forceinline__ void mfma_tile(const unsigned short* s_a,
                                          const unsigned short* s_b,
                                          int l16, int quad, int wbase, f32x4 acc[4]) {
    const unsigned short* ap = &s_a[(size_t)(wbase + l16) * WST + quad * 8];
    const unsigned short* bp = &s_b[(size_t)l16 * WST + quad * 8];
#pragma unroll
    for (int kt = 0; kt < 2; kt++) {
        bf16x8 a = *(const bf16x8*)(ap + kt * 32);
#pragma unroll
        for (int nt = 0; nt < 4; nt++) {
            bf16x8 b = *(const bf16x8*)(bp + (size_t)nt * 16 * WST + kt * 32);
            acc[nt] = __builtin_amdgcn_mfma_f32_16x16x32_bf16(a, b, acc[nt], 0, 0, 0);
        }
    }
}

// stage a pre-converted bf16 weight matrix (plain copy into padded LDS rows)
__device__ __forceinline__ void stage_wb(const unsigned short* __restrict__ wsrc,
                                         unsigned short* s_wb, int tid) {
    for (int i = tid; i < 512; i += 256) {
        int r = i >> 3, seg = i & 7;
        *(uint4*)(&s_wb[r * WST + seg * 8]) = ((const uint4*)(wsrc + r * 64))[seg];
    }
}

// ---------------- initial conv matmul: m = bf16(relu(x @ cw0^T)) ----------------

__global__ __launch_bounds__(256) void mm_relu_kernel(const float* __restrict__ h,
                                                      const unsigned short* __restrict__ wb,
                                                      __hip_bfloat16* __restrict__ m, int n) {
    __shared__ unsigned short s_hb[NPB * WST];
    __shared__ unsigned short s_wb[64 * WST];
    int tid = threadIdx.x;
    int base = blockIdx.x * NPB;
    stage_wb(wb, s_wb, tid);
    for (int i = tid; i < 512; i += 256) {
        int r = i >> 3, seg = i & 7;
        if (base + r < n) {
            const float4* hp = (const float4*)(h + (size_t)(base + r) * HIDDEN + seg * 8);
            float4 ha = hp[0], hb = hp[1];
            uint4 p;
            p.x = (unsigned int)f2b(ha.x) | ((unsigned int)f2b(ha.y) << 16);
            p.y = (unsigned int)f2b(ha.z) | ((unsigned int)f2b(ha.w) << 16);
            p.z = (unsigned int)f2b(hb.x) | ((unsigned int)f2b(hb.y) << 16);
            p.w = (unsigned int)f2b(hb.z) | ((unsigned int)f2b(hb.w) << 16);
            *(uint4*)(&s_hb[r * WST + seg * 8]) = p;
        } else {
            *(uint4*)(&s_hb[r * WST + seg * 8]) = make_uint4(0u, 0u, 0u, 0u);
        }
    }
    __syncthreads();
    int lane = tid & 63, wave = tid >> 6;
    int quad = lane >> 4, l16 = lane & 15;
    int wbase = wave * 16;
    f32x4 acc[4];
    acc[0] = (f32x4){0.f,0.f,0.f,0.f}; acc[1] = (f32x4){0.f,0.f,0.f,0.f};
    acc[2] = (f32x4){0.f,0.f,0.f,0.f}; acc[3] = (f32x4){0.f,0.f,0.f,0.f};
    mfma_tile(s_hb, s_wb, l16, quad, wbase, acc);
    unsigned short* mo = (unsigned short*)m;
#pragma unroll
    for (int r = 0; r < 4; r++) {
        int node = base + wbase + quad * 4 + r;
        if (node < n) {
#pragma unroll
            for (int nt = 0; nt < 4; nt++)
                mo[(size_t)node * HIDDEN + nt * 16 + l16] = f2b(fmaxf(acc[nt][r], 0.f));
        }
    }
}

// ---------------- aggregation ----------------
// Eight nodes per wave: group g = lane>>3 handles node 8w+g; lane owns 8
// channels (uint4 16B gathers; 8 lanes x 16B = one full m row per edge).
// 8 gather instructions in flight x 8 rows each = 8KB MLP per wave.
// Residual from f32 x (layer 0) or bf16 h buffer. Output h' bf16 only.
__global__ __launch_bounds__(256) void aggregate_kernel(const float* hf,
                                                        const __hip_bfloat16* hb_in,
                                                        const __hip_bfloat16* __restrict__ m,
                                                        const int* __restrict__ row_ptr,
                                                        const int* __restrict__ ecol,
                                                        const float* __restrict__ nw,
                                                        __hip_bfloat16* __restrict__ hb_out,
                                                        int n) {
    int lane = threadIdx.x & 63;
    int wave = (blockIdx.x * blockDim.x + threadIdx.x) >> 6;
    int grp = lane >> 3;
    int sl = lane & 7;
    int node = 8 * wave + grp;
    if (node >= n) return;
    int beg = row_ptr[node];
    int end = row_ptr[node + 1];
    float s[8];
    if (hf) {
        const float4* hp = (const float4*)(hf + (size_t)node * HIDDEN + 8 * sl);
        float4 v0 = hp[0], v1 = hp[1];
        s[0] = v0.x; s[1] = v0.y; s[2] = v0.z; s[3] = v0.w;
        s[4] = v1.x; s[5] = v1.y; s[6] = v1.z; s[7] = v1.w;
    } else {
        uint4 u = *(const uint4*)((const unsigned short*)hb_in + (size_t)node * HIDDEN + 8 * sl);
        s[0] = b2f_lo(u.x); s[1] = b2f_hi(u.x);
        s[2] = b2f_lo(u.y); s[3] = b2f_hi(u.y);
        s[4] = b2f_lo(u.z); s[5] = b2f_hi(u.z);
        s[6] = b2f_lo(u.w); s[7] = b2f_hi(u.w);
    }
    const unsigned short* mi = (const unsigned short*)m;
    float p0[8], p1[8];        // two partials per channel (short add chains)
#pragma unroll
    for (int q = 0; q < 8; q++) { p0[q] = 0.f; p1[q] = 0.f; }
    int sbase = grp * 8;
    for (int b0 = beg; b0 < end; b0 += 8) {
        int idx = b0 + sl;
        int myc = ecol[idx < end ? idx : end - 1];
        int cnt = end - b0;
        if (cnt > 8) cnt = 8;
        int c[8];
#pragma unroll
        for (int j = 0; j < 8; j++) c[j] = __shfl(myc, sbase + j, 64);
        uint4 u[8];
#pragma unroll
        for (int j = 0; j < 8; j++)
            u[j] = *(const uint4*)(mi + (size_t)c[j] * HIDDEN + 8 * sl);
#pragma unroll
        for (int j = 0; j < 8; j++) {
            bool ok = j < cnt;
            float* p = (j & 1) ? p1 : p0;
            p[0] += ok ? b2f_lo(u[j].x) : 0.f;
            p[1] += ok ? b2f_hi(u[j].x) : 0.f;
            p[2] += ok ? b2f_lo(u[j].y) : 0.f;
            p[3] += ok ? b2f_hi(u[j].y) : 0.f;
            p[4] += ok ? b2f_lo(u[j].z) : 0.f;
            p[5] += ok ? b2f_hi(u[j].z) : 0.f;
            p[6] += ok ? b2f_lo(u[j].w) : 0.f;
            p[7] += ok ? b2f_hi(u[j].w) : 0.f;
        }
    }
    float ss = 0.f;
#pragma unroll
    for (int q = 0; q < 8; q++) {
        s[q] += p0[q] + p1[q];
        ss += s[q] * s[q];
    }
#pragma unroll
    for (int off = 4; off > 0; off >>= 1) ss += __shfl_xor(ss, off, 64);
    float inv = rsqrtf(ss * (1.0f / 64.0f) + EPS);
    const float4* nwp = (const float4*)(nw + 8 * sl);
    float4 w0 = nwp[0], w1 = nwp[1];
    uint4 pb;
    pb.x = (unsigned int)f2b(s[0] * inv * w0.x) | ((unsigned int)f2b(s[1] * inv * w0.y) << 16);
    pb.y = (unsigned int)f2b(s[2] * inv * w0.z) | ((unsigned int)f2b(s[3] * inv * w0.w) << 16);
    pb.z = (unsigned int)f2b(s[4] * inv * w1.x) | ((unsigned int)f2b(s[5] * inv * w1.y) << 16);
    pb.w = (unsigned int)f2b(s[6] * inv * w1.z) | ((unsigned int)f2b(s[7] * inv * w1.w) << 16);
    *(uint4*)((unsigned short*)hb_out + (size_t)node * HIDDEN + 8 * sl) = pb;
}

// ---------------- fused hidden + next-conv kernel ----------------
// NPB2=128 nodes/block: each wave runs 2 independent 16-node tiles (B ->
// D->A writeback -> C per tile, all intra-wave; single barrier after staging).
// Residual from the bf16 LDS A-tile. Output: f32 d_out on last layer, bf16 h
// buffer otherwise. Phase C: m_out = bf16(relu(h_new @ cw_next^T)).

__global__ __launch_bounds__(256) void hidden_next_kernel(const __hip_bfloat16* __restrict__ hb_in,
                                                          const unsigned short* __restrict__ hwb,
                                                          const unsigned short* cwb_next,
                                                          const float* __restrict__ hnw,
                                                          float* out_f32,
                                                          __hip_bfloat16* hb_new,
                                                          __hip_bfloat16* m_out, int n) {
    __shared__ unsigned short s_hb[NPB2 * WST];
    __shared__ unsigned short s_wb[64 * WST];
    __shared__ unsigned short s_wb2[64 * WST];
    int tid = threadIdx.x;
    int base = blockIdx.x * NPB2;
    stage_wb(hwb, s_wb, tid);
    if (cwb_next) stage_wb(cwb_next, s_wb2, tid);
    const unsigned short* hbs = (const unsigned short*)hb_in;
    for (int i = tid; i < 1024; i += 256) {
        int r = i >> 3, seg = i & 7;
        uint4 p = make_uint4(0u, 0u, 0u, 0u);
        if (base + r < n) p = ((const uint4*)(hbs + (size_t)(base + r) * HIDDEN))[seg];
        *(uint4*)(&s_hb[r * WST + seg * 8]) = p;
    }
    __syncthreads();

    int lane = tid & 63, wave = tid >> 6;
    int quad = lane >> 4, l16 = lane & 15;

    float nwv[4];
#pragma unroll
    for (int nt = 0; nt < 4; nt++) nwv[nt] = hnw[nt * 16 + l16];

#pragma unroll
    for (int t = 0; t < 2; t++) {
        int wbase = wave * 16 + t * 64;

        // ---- Phase B ----
        f32x4 acc[4];
        acc[0] = (f32x4){0.f,0.f,0.f,0.f}; acc[1] = (f32x4){0.f,0.f,0.f,0.f};
        acc[2] = (f32x4){0.f,0.f,0.f,0.f}; acc[3] = (f32x4){0.f,0.f,0.f,0.f};
        mfma_tile(s_hb, s_wb, l16, quad, wbase, acc);

        float hv[4][4];
        float ssq[4] = {0.f, 0.f, 0.f, 0.f};
#pragma unroll
        for (int r = 0; r < 4; r++) {
            int nl = wbase + quad * 4 + r;
#pragma unroll
            for (int nt = 0; nt < 4; nt++) {
                float hres = b2f(s_hb[(size_t)nl * WST + nt * 16 + l16]);
                float v = hres + fmaxf(acc[nt][r], 0.f);
                hv[r][nt] = v;
                ssq[r] += v * v;
            }
        }
#pragma unroll
        for (int mk = 1; mk <= 8; mk <<= 1) {
#pragma unroll
            for (int r = 0; r < 4; r++) ssq[r] += __shfl_xor(ssq[r], mk, 64);
        }
#pragma unroll
        for (int r = 0; r < 4; r++) {
            float inv = rsqrtf(ssq[r] * (1.0f / 64.0f) + EPS);
#pragma unroll
            for (int nt = 0; nt < 4; nt++) hv[r][nt] *= inv * nwv[nt];
        }
        if (out_f32) {
#pragma unroll
            for (int r = 0; r < 4; r++) {
                int node = base + wbase + quad * 4 + r;
                if (node < n) {
#pragma unroll
                    for (int nt = 0; nt < 4; nt++)
                        out_f32[(size_t)node * HIDDEN + nt * 16 + l16] = hv[r][nt];
                }
            }
        }
        if (hb_new) {
            unsigned short* ho = (unsigned short*)hb_new;
#pragma unroll
            for (int r = 0; r < 4; r++) {
                int node = base + wbase + quad * 4 + r;
                if (node < n) {
#pragma unroll
                    for (int nt = 0; nt < 4; nt++)
                        ho[(size_t)node * HIDDEN + nt * 16 + l16] = f2b(hv[r][nt]);
                }
            }
        }

        if (!m_out) continue;

        // ---- D -> A layout (own rows only; intra-wave, no barrier) ----
#pragma unroll
        for (int r = 0; r < 4; r++) {
            int nl = wbase + quad * 4 + r;
#pragma unroll
            for (int nt = 0; nt < 4; nt++)
                s_hb[(size_t)nl * WST + nt * 16 + l16] = f2b(hv[r][nt]);
        }

        // ---- Phase C ----
        f32x4 acc2[4];
        acc2[0] = (f32x4){0.f,0.f,0.f,0.f}; acc2[1] = (f32x4){0.f,0.f,0.f,0.f};
        acc2[2] = (f32x4){0.f,0.f,0.f,0.f}; acc2[3] = (f32x4){0.f,0.f,0.f,0.f};
        mfma_tile(s_hb, s_wb2, l16, quad, wbase, acc2);
        unsigned short* mo = (unsigned short*)m_out;
#pragma unroll
        for (int r = 0; r < 4; r++) {
            int node = base + wbase + quad * 4 + r;
            if (node < n) {
#pragma unroll
                for (int nt = 0; nt < 4; nt++)
                    mo[(size_t)node * HIDDEN + nt * 16 + l16] = f2b(fmaxf(acc2[nt][r], 0.f));
            }
        }
    }
}

// ---------------- launch ----------------

static inline size_t align_up(size_t x, size_t a) { return (x + a - 1) & ~(a - 1); }

extern "C" void kernel_launch(void* const* d_in, const int* in_sizes, int n_in,
                              void* d_out, int out_size, void* d_ws, size_t ws_size,
                              hipStream_t stream) {
    const float* x       = (const float*)d_in[0];
    const float* conv_w  = (const float*)d_in[1];
    const float* conv_nw = (const float*)d_in[2];
    const float* hid_w   = (const float*)d_in[3];
    const float* hid_nw  = (const float*)d_in[4];
    const int*   row     = (const int*)d_in[5];
    const int*   col     = (const int*)d_in[6];
    float* out = (float*)d_out;

    const int n = in_sizes[0] / HIDDEN;   // 100000
    const int e = in_sizes[5];            // 800000
    const int L = in_sizes[1] / 4096;     // 4

    // workspace layout
    size_t off = 0;
    char* ws = (char*)d_ws;
    __hip_bfloat16* mA = (__hip_bfloat16*)(ws + off);  off = align_up(off + (size_t)n * HIDDEN * 2, 16);
    __hip_bfloat16* mB = (__hip_bfloat16*)(ws + off);  off = align_up(off + (size_t)n * HIDDEN * 2, 16);
    __hip_bfloat16* hb1 = (__hip_bfloat16*)(ws + off); off = align_up(off + (size_t)n * HIDDEN * 2, 16);
    __hip_bfloat16* hb2 = (__hip_bfloat16*)(ws + off); off = align_up(off + (size_t)n * HIDDEN * 2, 16);
    unsigned short* wbt = (unsigned short*)(ws + off); off = align_up(off + (size_t)2 * L * 4096 * 2, 16);
    int* row_ptr = (int*)(ws + off);           off = align_up(off + (size_t)(n + 1) * 4, 16);
    int* cnt = (int*)(ws + off);               off = align_up(off + (size_t)n * 4, 16);
    int* bsum = (int*)(ws + off);              off = align_up(off + (size_t)1024 * 4, 16);
    int* erank = (int*)(ws + off);             off = align_up(off + (size_t)e * 4, 16);
    int* ecol = (int*)(ws + off);              off = align_up(off + (size_t)e * 4, 16);

    const int nb = (n + 255) / 256;

    // CSR build (once per launch; edges constant across layers)
    hipMemsetAsync(cnt, 0, (size_t)n * 4, stream);
    hist_rank_kernel<<<1024, 256, 0, stream>>>(row, cnt, erank, e);
    block_sum_kernel<<<nb, 256, 0, stream>>>(cnt, bsum, n);
    scan_bsum_kernel<<<1, 1024, 0, stream>>>(bsum, nb, row_ptr + n);
    scan_final_kernel<<<nb, 256, 0, stream>>>(cnt, bsum, row_ptr, n);
    fill_kernel<<<1024, 256, 0, stream>>>(row, col, row_ptr, erank, ecol, e, n);

    // weights -> bf16 once
    wconv_kernel<<<(2 * L * 4096 + 255) / 256, 256, 0, stream>>>(conv_w, hid_w, wbt, L);

    const int blocks = (n + NPB - 1) / NPB;
    const int hblocks = (n + NPB2 - 1) / NPB2;
    const int agg_blocks = (((n + 7) / 8) * 64 + 255) / 256;   // eight nodes per wave

    // initial conv matmul for layer 0
    mm_relu_kernel<<<blocks, 256, 0, stream>>>(x, wbt, mA, n);

    const __hip_bfloat16* mi = mA;
    __hip_bfloat16* mo = mB;
    for (int l = 0; l < L; l++) {
        aggregate_kernel<<<agg_blocks, 256, 0, stream>>>(
            (l == 0) ? x : nullptr, (l == 0) ? nullptr : hb2, mi, row_ptr, ecol,
            conv_nw + (size_t)l * HIDDEN, hb1, n);
        bool last = (l == L - 1);
        hidden_next_kernel<<<hblocks, 256, 0, stream>>>(
            hb1, wbt + (size_t)(L + l) * 4096,
            last ? nullptr : (wbt + (size_t)(l + 1) * 4096),
            hid_nw + (size_t)l * HIDDEN,
            last ? out : nullptr,
            last ? nullptr : hb2,
            last ? nullptr : mo, n);
        __hip_bfloat16* tmp = (__hip_bfloat16*)mi; mi = mo; mo = tmp;
    }
}

// Round 11
// 274.548 us; speedup vs baseline: 1.8526x; 1.0411x over previous
//
#include <hip/hip_runtime.h>
#include <hip/hip_bf16.h>

#define HIDDEN 64
#define EPS 1e-5f
#define NPB 64            // nodes per block (mm_relu and fused layer)
#define WST 72            // bf16 LDS row stride (shorts): 16B-aligned, breaks 128B aliasing

typedef __attribute__((ext_vector_type(8))) short bf16x8;   // MFMA A/B frag (4 VGPRs)
typedef __attribute__((ext_vector_type(4))) float f32x4;    // MFMA C/D frag

__device__ __forceinline__ unsigned short f2b(float x) {
    __hip_bfloat16 b = __float2bfloat16(x);
    return *(unsigned short*)&b;
}
__device__ __forceinline__ float b2f(unsigned short u) {
    unsigned int ui = (unsigned int)u << 16;
    return *(float*)&ui;
}
__device__ __forceinline__ float b2f_lo(unsigned int u) { unsigned int ui = u << 16; return *(float*)&ui; }
__device__ __forceinline__ float b2f_hi(unsigned int u) { unsigned int ui = u & 0xffff0000u; return *(float*)&ui; }

// ---------------- CSR build ----------------

__global__ __launch_bounds__(256) void hist_rank_kernel(const int* __restrict__ row,
                                                        int* __restrict__ cnt,
                                                        int* __restrict__ erank, int e) {
    int stride = gridDim.x * blockDim.x;
    for (int i = blockIdx.x * blockDim.x + threadIdx.x; i < e; i += stride) {
        int r = row[i];
        erank[i] = atomicAdd(&cnt[r], 1);
    }
}

__global__ __launch_bounds__(256) void block_sum_kernel(const int* __restrict__ cnt,
                                                        int* __restrict__ bsum, int n) {
    __shared__ int wsum[4];
    int tid = threadIdx.x;
    int i = blockIdx.x * 256 + tid;
    int v = (i < n) ? cnt[i] : 0;
#pragma unroll
    for (int off = 32; off > 0; off >>= 1) v += __shfl_xor(v, off, 64);
    if ((tid & 63) == 0) wsum[tid >> 6] = v;
    __syncthreads();
    if (tid == 0) bsum[blockIdx.x] = wsum[0] + wsum[1] + wsum[2] + wsum[3];
}

// scan_final with inline block-prefix: block b sums bsum[0..b) itself
// (<=nb L2-hot ints), does its local 256-scan, writes row_ptr; last block
// also writes row_ptr[n]. Replaces the old separate scan_bsum dispatch.
__global__ __launch_bounds__(256) void scan_final_kernel(const int* __restrict__ cnt,
                                                         const int* __restrict__ bsum,
                                                         int* __restrict__ row_ptr,
                                                         int n, int nb) {
    __shared__ int wred[4];
    __shared__ int wsum[4];
    __shared__ int wexcl[4];
    __shared__ int s_prev;
    __shared__ int s_tot;
    int b = blockIdx.x;
    int tid = threadIdx.x;
    int lane = tid & 63;
    int w = tid >> 6;
    // prefix over previous blocks
    int acc = 0;
    for (int j = tid; j < b; j += 256) acc += bsum[j];
#pragma unroll
    for (int off = 32; off > 0; off >>= 1) acc += __shfl_xor(acc, off, 64);
    if (lane == 0) wred[w] = acc;
    // local inclusive scan
    int i = b * 256 + tid;
    int v = (i < n) ? cnt[i] : 0;
    int sc = v;
#pragma unroll
    for (int off = 1; off < 64; off <<= 1) {
        int t = __shfl_up(sc, off, 64);
        if (lane >= off) sc += t;
    }
    if (lane == 63) wsum[w] = sc;
    __syncthreads();
    if (tid == 0) {
        s_prev = wred[0] + wred[1] + wred[2] + wred[3];
        int a = 0;
#pragma unroll
        for (int j = 0; j < 4; j++) { wexcl[j] = a; a += wsum[j]; }
        s_tot = a;
    }
    __syncthreads();
    if (i < n) row_ptr[i] = s_prev + wexcl[w] + (sc - v);
    if (b == nb - 1 && tid == 0) row_ptr[n] = s_prev + s_tot;
}

__global__ __launch_bounds__(256) void fill_kernel(const int* __restrict__ row,
                                                   const int* __restrict__ col,
                                                   const int* __restrict__ row_ptr,
                                                   const int* __restrict__ erank,
                                                   int* __restrict__ ecol, int e, int n) {
    int cls = blockIdx.x & 7;
    int sub = blockIdx.x >> 3;
    int nsub = gridDim.x >> 3;
    int lo = (int)(((long long)n * cls) >> 3);
    int hi = (int)(((long long)n * (cls + 1)) >> 3);
    for (int i = sub * 256 + threadIdx.x; i < e; i += nsub * 256) {
        int r = row[i];
        if (r >= lo && r < hi) {
            int pos = row_ptr[r] + erank[i];
            ecol[pos] = col[i];
        }
    }
}

// pre-convert all 2L weight matrices to bf16, [o][k] row-major (= MFMA B layout)
__global__ __launch_bounds__(256) void wconv_kernel(const float* __restrict__ cw,
                                                    const float* __restrict__ hw,
                                                    unsigned short* __restrict__ wbt, int L) {
    int idx = blockIdx.x * blockDim.x + threadIdx.x;
    int total = 2 * L * 4096;
    if (idx >= total) return;
    int mat = idx >> 12;
    int rem = idx & 4095;
    const float* src = (mat < L) ? (cw + (size_t)mat * 4096) : (hw + (size_t)(mat - L) * 4096);
    wbt[idx] = f2b(src[rem]);
}

// ---------------- MFMA helpers ----------------
// A tile: s_a[node][k] bf16 stride WST; wave computes nodes wbase..wbase+15.
// B tile: s_b[o][k] bf16 stride WST. D layout: col=l16, row=quad*4+reg.

__device__ __forceinline__ void mfma_tile(const unsigned short* s_a,
                                          const unsigned short* s_b,
                                          int l16, int quad, int wbase, f32x4 acc[4]) {
    const unsigned short* ap = &s_a[(size_t)(wbase + l16) * WST + quad * 8];
    const unsigned short* bp = &s_b[(size_t)l16 * WST + quad * 8];
#pragma unroll
    for (int kt = 0; kt < 2; kt++) {
        bf16x8 a = *(const bf16x8*)(ap + kt * 32);
#pragma unroll
        for (int nt = 0; nt < 4; nt++) {
            bf16x8 b = *(const bf16x8*)(bp + (size_t)nt * 16 * WST + kt * 32);
            acc[nt] = __builtin_amdgcn_mfma_f32_16x16x32_bf16(a, b, acc[nt], 0, 0, 0);
        }
    }
}

// stage a pre-converted bf16 weight matrix (plain copy into padded LDS rows)
__device__ __forceinline__ void stage_wb(const unsigned short* __restrict__ wsrc,
                                         unsigned short* s_wb, int tid) {
    for (int i = tid; i < 512; i += 256) {
        int r = i >> 3, seg = i & 7;
        *(uint4*)(&s_wb[r * WST + seg * 8]) = ((const uint4*)(wsrc + r * 64))[seg];
    }
}

// ---------------- initial conv matmul: m = bf16(relu(x @ cw0^T)) ----------------

__global__ __launch_bounds__(256) void mm_relu_kernel(const float* __restrict__ h,
                                                      const unsigned short* __restrict__ wb,
                                                      __hip_bfloat16* __restrict__ m, int n) {
    __shared__ unsigned short s_hb[NPB * WST];
    __shared__ unsigned short s_wb[64 * WST];
    int tid = threadIdx.x;
    int base = blockIdx.x * NPB;
    stage_wb(wb, s_wb, tid);
    for (int i = tid; i < 512; i += 256) {
        int r = i >> 3, seg = i & 7;
        if (base + r < n) {
            const float4* hp = (const float4*)(h + (size_t)(base + r) * HIDDEN + seg * 8);
            float4 ha = hp[0], hb = hp[1];
            uint4 p;
            p.x = (unsigned int)f2b(ha.x) | ((unsigned int)f2b(ha.y) << 16);
            p.y = (unsigned int)f2b(ha.z) | ((unsigned int)f2b(ha.w) << 16);
            p.z = (unsigned int)f2b(hb.x) | ((unsigned int)f2b(hb.y) << 16);
            p.w = (unsigned int)f2b(hb.z) | ((unsigned int)f2b(hb.w) << 16);
            *(uint4*)(&s_hb[r * WST + seg * 8]) = p;
        } else {
            *(uint4*)(&s_hb[r * WST + seg * 8]) = make_uint4(0u, 0u, 0u, 0u);
        }
    }
    __syncthreads();
    int lane = tid & 63, wave = tid >> 6;
    int quad = lane >> 4, l16 = lane & 15;
    int wbase = wave * 16;
    f32x4 acc[4];
    acc[0] = (f32x4){0.f,0.f,0.f,0.f}; acc[1] = (f32x4){0.f,0.f,0.f,0.f};
    acc[2] = (f32x4){0.f,0.f,0.f,0.f}; acc[3] = (f32x4){0.f,0.f,0.f,0.f};
    mfma_tile(s_hb, s_wb, l16, quad, wbase, acc);
    unsigned short* mo = (unsigned short*)m;
#pragma unroll
    for (int r = 0; r < 4; r++) {
        int node = base + wbase + quad * 4 + r;
        if (node < n) {
#pragma unroll
            for (int nt = 0; nt < 4; nt++)
                mo[(size_t)node * HIDDEN + nt * 16 + l16] = f2b(fmaxf(acc[nt][r], 0.f));
        }
    }
}

// ---------------- fused layer kernel ----------------
// Block = 256 thr = 4 waves, 64 nodes. Wave w owns nodes wbase..wbase+15 —
// exactly its MFMA A-tile rows, so phase A -> B needs NO barrier.
// Phase A: 8 nodes per wave-round (2 rounds), bulk-ecol + uint4 gathers
//          (R9/R10-proven), conv rmsnorm -> h' bf16 straight into LDS A-tile.
// Weights are cooperatively staged BEFORE phase A; the single __syncthreads
// after phase A only orders weight visibility (writes long since done).
// Phase B: hidden MFMA + residual (own LDS rows) + rmsnorm -> h_new:
//          bf16 hb_new (next layer) or f32 d_out (last layer).
// Phase C: MFMA with next conv weights -> relu -> m_out (double-buffered).

__global__ __launch_bounds__(256) void fused_layer_kernel(
        const float* hf, const __hip_bfloat16* hb_in,
        const __hip_bfloat16* __restrict__ m_in,
        const unsigned short* __restrict__ hwb,
        const unsigned short* cwb_next,
        const int* __restrict__ row_ptr, const int* __restrict__ ecol,
        const float* __restrict__ cnw, const float* __restrict__ hnw,
        float* out_f32, __hip_bfloat16* hb_new, __hip_bfloat16* m_out, int n) {
    __shared__ unsigned short s_hb[NPB * WST];
    __shared__ unsigned short s_wb[64 * WST];
    __shared__ unsigned short s_wb2[64 * WST];
    int tid = threadIdx.x;
    int base = blockIdx.x * NPB;
    int lane = tid & 63, wave = tid >> 6;

    // stage weights early (completes during phase A)
    stage_wb(hwb, s_wb, tid);
    if (cwb_next) stage_wb(cwb_next, s_wb2, tid);

    // ---- Phase A: aggregate this wave's 16 nodes (2 rounds x 8 nodes) ----
    int grp = lane >> 3;
    int sl = lane & 7;
    int sbase = grp * 8;
    const float4* cp = (const float4*)(cnw + 8 * sl);
    float4 c0 = cp[0], c1 = cp[1];
    const unsigned short* mi = (const unsigned short*)m_in;

#pragma unroll
    for (int rnd = 0; rnd < 2; rnd++) {
        int nl = wave * 16 + rnd * 8 + grp;
        int node = base + nl;
        uint4 pb = make_uint4(0u, 0u, 0u, 0u);
        if (node < n) {
            float s[8];
            if (hf) {
                const float4* hp = (const float4*)(hf + (size_t)node * HIDDEN + 8 * sl);
                float4 v0 = hp[0], v1 = hp[1];
                s[0] = v0.x; s[1] = v0.y; s[2] = v0.z; s[3] = v0.w;
                s[4] = v1.x; s[5] = v1.y; s[6] = v1.z; s[7] = v1.w;
            } else {
                uint4 u = *(const uint4*)((const unsigned short*)hb_in + (size_t)node * HIDDEN + 8 * sl);
                s[0] = b2f_lo(u.x); s[1] = b2f_hi(u.x);
                s[2] = b2f_lo(u.y); s[3] = b2f_hi(u.y);
                s[4] = b2f_lo(u.z); s[5] = b2f_hi(u.z);
                s[6] = b2f_lo(u.w); s[7] = b2f_hi(u.w);
            }
            int beg = row_ptr[node];
            int end = row_ptr[node + 1];
            float p0[8], p1[8];
#pragma unroll
            for (int q = 0; q < 8; q++) { p0[q] = 0.f; p1[q] = 0.f; }
            for (int b0 = beg; b0 < end; b0 += 8) {
                int idx = b0 + sl;
                int myc = ecol[idx < end ? idx : end - 1];
                int cnt = end - b0;
                if (cnt > 8) cnt = 8;
                int c[8];
#pragma unroll
                for (int j = 0; j < 8; j++) c[j] = __shfl(myc, sbase + j, 64);
                uint4 u[8];
#pragma unroll
                for (int j = 0; j < 8; j++)
                    u[j] = *(const uint4*)(mi + (size_t)c[j] * HIDDEN + 8 * sl);
#pragma unroll
                for (int j = 0; j < 8; j++) {
                    bool ok = j < cnt;
                    float* p = (j & 1) ? p1 : p0;
                    p[0] += ok ? b2f_lo(u[j].x) : 0.f;
                    p[1] += ok ? b2f_hi(u[j].x) : 0.f;
                    p[2] += ok ? b2f_lo(u[j].y) : 0.f;
                    p[3] += ok ? b2f_hi(u[j].y) : 0.f;
                    p[4] += ok ? b2f_lo(u[j].z) : 0.f;
                    p[5] += ok ? b2f_hi(u[j].z) : 0.f;
                    p[6] += ok ? b2f_lo(u[j].w) : 0.f;
                    p[7] += ok ? b2f_hi(u[j].w) : 0.f;
                }
            }
            float ss = 0.f;
#pragma unroll
            for (int q = 0; q < 8; q++) {
                s[q] += p0[q] + p1[q];
                ss += s[q] * s[q];
            }
#pragma unroll
            for (int off = 4; off > 0; off >>= 1) ss += __shfl_xor(ss, off, 64);
            float inv = rsqrtf(ss * (1.0f / 64.0f) + EPS);
            pb.x = (unsigned int)f2b(s[0] * inv * c0.x) | ((unsigned int)f2b(s[1] * inv * c0.y) << 16);
            pb.y = (unsigned int)f2b(s[2] * inv * c0.z) | ((unsigned int)f2b(s[3] * inv * c0.w) << 16);
            pb.z = (unsigned int)f2b(s[4] * inv * c1.x) | ((unsigned int)f2b(s[5] * inv * c1.y) << 16);
            pb.w = (unsigned int)f2b(s[6] * inv * c1.z) | ((unsigned int)f2b(s[7] * inv * c1.w) << 16);
        }
        *(uint4*)(&s_hb[(size_t)nl * WST + 8 * sl]) = pb;
    }
    __syncthreads();   // weight-tile visibility (A-tile rows are wave-private)

    // ---- Phase B ----
    int quad = lane >> 4, l16 = lane & 15;
    int wbase = wave * 16;
    f32x4 acc[4];
    acc[0] = (f32x4){0.f,0.f,0.f,0.f}; acc[1] = (f32x4){0.f,0.f,0.f,0.f};
    acc[2] = (f32x4){0.f,0.f,0.f,0.f}; acc[3] = (f32x4){0.f,0.f,0.f,0.f};
    mfma_tile(s_hb, s_wb, l16, quad, wbase, acc);

    float hv[4][4];
    float ssq[4] = {0.f, 0.f, 0.f, 0.f};
#pragma unroll
    for (int r = 0; r < 4; r++) {
        int nl = wbase + quad * 4 + r;
#pragma unroll
        for (int nt = 0; nt < 4; nt++) {
            float hres = b2f(s_hb[(size_t)nl * WST + nt * 16 + l16]);
            float v = hres + fmaxf(acc[nt][r], 0.f);
            hv[r][nt] = v;
            ssq[r] += v * v;
        }
    }
#pragma unroll
    for (int mk = 1; mk <= 8; mk <<= 1) {
#pragma unroll
        for (int r = 0; r < 4; r++) ssq[r] += __shfl_xor(ssq[r], mk, 64);
    }
    float nwv[4];
#pragma unroll
    for (int nt = 0; nt < 4; nt++) nwv[nt] = hnw[nt * 16 + l16];
#pragma unroll
    for (int r = 0; r < 4; r++) {
        float inv = rsqrtf(ssq[r] * (1.0f / 64.0f) + EPS);
#pragma unroll
        for (int nt = 0; nt < 4; nt++) hv[r][nt] *= inv * nwv[nt];
    }
    if (out_f32) {
#pragma unroll
        for (int r = 0; r < 4; r++) {
            int node = base + wbase + quad * 4 + r;
            if (node < n) {
#pragma unroll
                for (int nt = 0; nt < 4; nt++)
                    out_f32[(size_t)node * HIDDEN + nt * 16 + l16] = hv[r][nt];
            }
        }
    }
    if (hb_new) {
        unsigned short* ho = (unsigned short*)hb_new;
#pragma unroll
        for (int r = 0; r < 4; r++) {
            int node = base + wbase + quad * 4 + r;
            if (node < n) {
#pragma unroll
                for (int nt = 0; nt < 4; nt++)
                    ho[(size_t)node * HIDDEN + nt * 16 + l16] = f2b(hv[r][nt]);
            }
        }
    }

    if (!m_out) return;

    // ---- D -> A layout (own rows only; intra-wave, no barrier) ----
#pragma unroll
    for (int r = 0; r < 4; r++) {
        int nl = wbase + quad * 4 + r;
#pragma unroll
        for (int nt = 0; nt < 4; nt++)
            s_hb[(size_t)nl * WST + nt * 16 + l16] = f2b(hv[r][nt]);
    }

    // ---- Phase C ----
    f32x4 acc2[4];
    acc2[0] = (f32x4){0.f,0.f,0.f,0.f}; acc2[1] = (f32x4){0.f,0.f,0.f,0.f};
    acc2[2] = (f32x4){0.f,0.f,0.f,0.f}; acc2[3] = (f32x4){0.f,0.f,0.f,0.f};
    mfma_tile(s_hb, s_wb2, l16, quad, wbase, acc2);
    unsigned short* mo = (unsigned short*)m_out;
#pragma unroll
    for (int r = 0; r < 4; r++) {
        int node = base + wbase + quad * 4 + r;
        if (node < n) {
#pragma unroll
            for (int nt = 0; nt < 4; nt++)
                mo[(size_t)node * HIDDEN + nt * 16 + l16] = f2b(fmaxf(acc2[nt][r], 0.f));
        }
    }
}

// ---------------- launch ----------------

static inline size_t align_up(size_t x, size_t a) { return (x + a - 1) & ~(a - 1); }

extern "C" void kernel_launch(void* const* d_in, const int* in_sizes, int n_in,
                              void* d_out, int out_size, void* d_ws, size_t ws_size,
                              hipStream_t stream) {
    const float* x       = (const float*)d_in[0];
    const float* conv_w  = (const float*)d_in[1];
    const float* conv_nw = (const float*)d_in[2];
    const float* hid_w   = (const float*)d_in[3];
    const float* hid_nw  = (const float*)d_in[4];
    const int*   row     = (const int*)d_in[5];
    const int*   col     = (const int*)d_in[6];
    float* out = (float*)d_out;

    const int n = in_sizes[0] / HIDDEN;   // 100000
    const int e = in_sizes[5];            // 800000
    const int L = in_sizes[1] / 4096;     // 4

    // workspace layout
    size_t off = 0;
    char* ws = (char*)d_ws;
    __hip_bfloat16* mA = (__hip_bfloat16*)(ws + off);  off = align_up(off + (size_t)n * HIDDEN * 2, 16);
    __hip_bfloat16* mB = (__hip_bfloat16*)(ws + off);  off = align_up(off + (size_t)n * HIDDEN * 2, 16);
    __hip_bfloat16* hb1 = (__hip_bfloat16*)(ws + off); off = align_up(off + (size_t)n * HIDDEN * 2, 16);
    __hip_bfloat16* hb2 = (__hip_bfloat16*)(ws + off); off = align_up(off + (size_t)n * HIDDEN * 2, 16);
    unsigned short* wbt = (unsigned short*)(ws + off); off = align_up(off + (size_t)2 * L * 4096 * 2, 16);
    int* row_ptr = (int*)(ws + off);           off = align_up(off + (size_t)(n + 1) * 4, 16);
    int* cnt = (int*)(ws + off);               off = align_up(off + (size_t)n * 4, 16);
    int* bsum = (int*)(ws + off);              off = align_up(off + (size_t)1024 * 4, 16);
    int* erank = (int*)(ws + off);             off = align_up(off + (size_t)e * 4, 16);
    int* ecol = (int*)(ws + off);              off = align_up(off + (size_t)e * 4, 16);

    const int nb = (n + 255) / 256;

    // CSR build (once per launch; edges constant across layers)
    hipMemsetAsync(cnt, 0, (size_t)n * 4, stream);
    hist_rank_kernel<<<1024, 256, 0, stream>>>(row, cnt, erank, e);
    block_sum_kernel<<<nb, 256, 0, stream>>>(cnt, bsum, n);
    scan_final_kernel<<<nb, 256, 0, stream>>>(cnt, bsum, row_ptr, n, nb);
    fill_kernel<<<1024, 256, 0, stream>>>(row, col, row_ptr, erank, ecol, e, n);

    // weights -> bf16 once
    wconv_kernel<<<(2 * L * 4096 + 255) / 256, 256, 0, stream>>>(conv_w, hid_w, wbt, L);

    const int blocks = (n + NPB - 1) / NPB;

    // initial conv matmul for layer 0
    mm_relu_kernel<<<blocks, 256, 0, stream>>>(x, wbt, mA, n);

    const __hip_bfloat16* mi = mA;
    __hip_bfloat16* mo = mB;
    __hip_bfloat16* hin = nullptr;   // layer 0 uses x (f32)
    __hip_bfloat16* hout = hb1;
    for (int l = 0; l < L; l++) {
        bool last = (l == L - 1);
        fused_layer_kernel<<<blocks, 256, 0, stream>>>(
            (l == 0) ? x : nullptr, hin, mi,
            wbt + (size_t)(L + l) * 4096,
            last ? nullptr : (wbt + (size_t)(l + 1) * 4096),
            row_ptr, ecol,
            conv_nw + (size_t)l * HIDDEN, hid_nw + (size_t)l * HIDDEN,
            last ? out : nullptr,
            last ? nullptr : hout,
            last ? nullptr : mo, n);
        __hip_bfloat16* tmp = (__hip_bfloat16*)mi; mi = mo; mo = tmp;
        hin = hout;
        hout = (hout == hb1) ? hb2 : hb1;
    }
}